// Round 10
// baseline (437.074 us; speedup 1.0000x reference)
//
#include <hip/hip_runtime.h>
#include <cstddef>
#include <cstdint>

#define B_   128
#define L_   31
#define D_   1024
#define DI_  2048
#define DS_  16
#define DC_  5
#define DTR_ 64
#define ROWS (B_ * L_)   // 3968
#define KCLS (L_ * D_)   // 31744

// weight-buffer offsets (u16 elements)
#define W_IN  0          // 4096x1024
#define W_OUT 4194304    // 1024x2048
#define W_F1  6291456    // 2048x1024
#define W_F2  8388608    // 1024x2048
#define W_XP  10485760   // 128x2048 (rows 96..127 zero)
#define W_DT  10747904   // 2048x64
#define WTOT  10878976

typedef unsigned short u16;
typedef __attribute__((ext_vector_type(8))) short s16x8;
typedef __attribute__((ext_vector_type(4))) float f32x4;

__device__ __forceinline__ float silu_f(float x) { return x / (1.0f + __expf(-x)); }

__device__ __forceinline__ u16 f2b(float f) {
    union { float f; uint32_t u; } c; c.f = f;
    uint32_t u = c.u + 0x7FFF + ((c.u >> 16) & 1);
    return (u16)(u >> 16);
}
__device__ __forceinline__ float b2f(u16 b) {
    union { uint32_t u; float f; } c; c.u = ((uint32_t)b) << 16;
    return c.f;
}
__device__ __forceinline__ uint32_t pack2(float lo, float hi) {
    return (uint32_t)f2b(lo) | ((uint32_t)f2b(hi) << 16);
}
__device__ __forceinline__ void cvt8(const float* __restrict__ s, u16* __restrict__ d) {
    const float4* p = (const float4*)s;
    float4 a = p[0], b = p[1];
    uint4 r;
    r.x = pack2(a.x, a.y); r.y = pack2(a.z, a.w);
    r.z = pack2(b.x, b.y); r.w = pack2(b.z, b.w);
    *(uint4*)d = r;
}

#define GLD16(g, s) __builtin_amdgcn_global_load_lds( \
    (const __attribute__((address_space(1))) void*)(g), \
    (__attribute__((address_space(3))) void*)(s), 16, 0, 0)

// ---------------- all-weights fp32 -> bf16 (single launch) ----------------
__global__ __launch_bounds__(256) void f2b_all_kernel(
    const float* __restrict__ inW, const float* __restrict__ outW,
    const float* __restrict__ f1W, const float* __restrict__ f2W,
    const float* __restrict__ xpW, const float* __restrict__ dtW,
    u16* __restrict__ wbuf)
{
    int g = blockIdx.x * 256 + threadIdx.x;
    if (g < 524288) { cvt8(inW + (size_t)g * 8, wbuf + W_IN + (size_t)g * 8); return; }
    g -= 524288;
    if (g < 262144) { cvt8(outW + (size_t)g * 8, wbuf + W_OUT + (size_t)g * 8); return; }
    g -= 262144;
    if (g < 262144) { cvt8(f1W + (size_t)g * 8, wbuf + W_F1 + (size_t)g * 8); return; }
    g -= 262144;
    if (g < 262144) { cvt8(f2W + (size_t)g * 8, wbuf + W_F2 + (size_t)g * 8); return; }
    g -= 262144;
    if (g < 32768) {   // x_proj, padded 96 -> 128 rows
        const int row = g >> 8, col8 = (g & 255) * 8;
        u16* d = wbuf + W_XP + (size_t)row * 2048 + col8;
        if (row < 96) cvt8(xpW + (size_t)row * 2048 + col8, d);
        else *(uint4*)d = make_uint4(0, 0, 0, 0);
        return;
    }
    g -= 32768;
    if (g < 16384) cvt8(dtW + (size_t)g * 8, wbuf + W_DT + (size_t)g * 8);
}

// ---------------- LayerNorm (one block per row, D=1024) -> bf16 out ----------------
__global__ __launch_bounds__(256) void ln_kernel(const float* __restrict__ x,
                                                 const float* __restrict__ w,
                                                 const float* __restrict__ b,
                                                 u16* __restrict__ y)
{
    const int row = blockIdx.x;
    const float* xr = x + (size_t)row * D_;
    float v[4];
    float sum = 0.f, sq = 0.f;
#pragma unroll
    for (int i = 0; i < 4; i++) {
        v[i] = xr[threadIdx.x + i * 256];
        sum += v[i];
        sq  += v[i] * v[i];
    }
#pragma unroll
    for (int o = 32; o > 0; o >>= 1) {
        sum += __shfl_down(sum, o, 64);
        sq  += __shfl_down(sq, o, 64);
    }
    __shared__ float red[8];
    const int wid = threadIdx.x >> 6;
    if ((threadIdx.x & 63) == 0) { red[wid] = sum; red[4 + wid] = sq; }
    __syncthreads();
    sum = red[0] + red[1] + red[2] + red[3];
    sq  = red[4] + red[5] + red[6] + red[7];
    const float mean = sum * (1.0f / D_);
    const float var  = sq * (1.0f / D_) - mean * mean;
    const float rstd = rsqrtf(var + 1e-5f);
    u16* yr = y + (size_t)row * D_;
#pragma unroll
    for (int i = 0; i < 4; i++) {
        const int c = threadIdx.x + i * 256;
        yr[c] = f2b((v[i] - mean) * rstd * w[c] + b[c]);
    }
}

// ---------------- fused: x2 = x + p0 + p1; h2 = LN(x2) -> bf16 ----------------
__global__ __launch_bounds__(256) void ln2_fuse_kernel(const float* __restrict__ x,
                                                       const float* __restrict__ p0,
                                                       const float* __restrict__ p1,
                                                       const float* __restrict__ w,
                                                       const float* __restrict__ b,
                                                       float* __restrict__ x2,
                                                       u16* __restrict__ y)
{
    const int row = blockIdx.x;
    const size_t base = (size_t)row * D_;
    float v[4];
    float sum = 0.f, sq = 0.f;
#pragma unroll
    for (int i = 0; i < 4; i++) {
        const int c = threadIdx.x + i * 256;
        const float s = x[base + c] + p0[base + c] + p1[base + c];
        x2[base + c] = s;
        v[i] = s;
        sum += s;
        sq  += s * s;
    }
#pragma unroll
    for (int o = 32; o > 0; o >>= 1) {
        sum += __shfl_down(sum, o, 64);
        sq  += __shfl_down(sq, o, 64);
    }
    __shared__ float red[8];
    const int wid = threadIdx.x >> 6;
    if ((threadIdx.x & 63) == 0) { red[wid] = sum; red[4 + wid] = sq; }
    __syncthreads();
    sum = red[0] + red[1] + red[2] + red[3];
    sq  = red[4] + red[5] + red[6] + red[7];
    const float mean = sum * (1.0f / D_);
    const float var  = sq * (1.0f / D_) - mean * mean;
    const float rstd = rsqrtf(var + 1e-5f);
    u16* yr = y + base;
#pragma unroll
    for (int i = 0; i < 4; i++) {
        const int c = threadIdx.x + i * 256;
        yr[c] = f2b((v[i] - mean) * rstd * w[c] + b[c]);
    }
}

// ---------------- x3 = x2 + q0 + q1 + b2 (vectorized) ----------------
__global__ __launch_bounds__(256) void add3_bias_kernel(const float* __restrict__ x2,
                                                        const float* __restrict__ q0,
                                                        const float* __restrict__ q1,
                                                        const float* __restrict__ b2,
                                                        float* __restrict__ x3)
{
    const int i = blockIdx.x * 256 + threadIdx.x;   // float4 index over ROWS*1024/4
    float4 a  = ((const float4*)x2)[i];
    float4 c0 = ((const float4*)q0)[i];
    float4 c1 = ((const float4*)q1)[i];
    float4 bb = ((const float4*)b2)[i & 255];
    float4 r;
    r.x = a.x + c0.x + c1.x + bb.x;
    r.y = a.y + c0.y + c1.y + bb.y;
    r.z = a.z + c0.z + c1.z + bb.z;
    r.w = a.w + c0.w + c1.w + bb.w;
    ((float4*)x3)[i] = r;
}

// ======== 128x128-tile bf16 MFMA GEMM, BK=64, 4 waves, XOR-swizzled LDS ========
// R9-proven: m97 2-barrier skeleton, BK=64 (half the barrier drains, 32 KB LDS
// keeps ~4 blocks/CU), both-sides swizzle (source granule sg^(srow&7), read
// granule (ks*4+lhi)^(lane15&7)) -> 2-way max bank aliasing (free, m136).
// ACT: 0 none, 1 silu, 2 softplus. OUT: 1 bf16, 2 f32 atomicAdd, 3 f32 partial.
template <int ACT, bool BIAS, int OUT>
__global__ __launch_bounds__(256) void gemm128_bk64(
    const u16* __restrict__ A, const u16* __restrict__ W,
    const float* __restrict__ bias, void* __restrict__ Cout,
    int M, int K, int Nout, int kLen)
{
    __shared__ __align__(16) u16 As[128 * 64];   // 16 KB
    __shared__ __align__(16) u16 Bs[128 * 64];   // 16 KB
    const int tid = threadIdx.x;
    const int l = tid & 63, w = tid >> 6;
    const int bm = blockIdx.y * 128, bn = blockIdx.x * 128;
    const int kOff = blockIdx.z * kLen;

    const int srow = tid >> 3;                   // 0..31
    const int sg   = tid & 7;                    // LDS granule slot (linear)
    const int sgx  = sg ^ (srow & 7);            // swizzled SOURCE granule
    const u16* gA = A + (size_t)(bm + srow) * K + kOff + sgx * 8;
    const u16* gB = W + (size_t)(bn + srow) * K + kOff + sgx * 8;
    const int soff = srow * 64 + sg * 8;         // == tid*8 (lane-linear)

    const int lane15 = l & 15, lhi = l >> 4;
    const int key = lane15 & 7;
    const int wr = w >> 1, wc = w & 1;
    const u16* fArow = As + (wr * 64 + lane15) * 64;
    const u16* fBrow = Bs + (wc * 64 + lane15) * 64;

    f32x4 acc[4][4] = {};

    for (int kk = 0; kk < kLen; kk += 64) {
#pragma unroll
        for (int c = 0; c < 4; c++) {
            GLD16(gA + (size_t)c * 32 * K, As + c * 2048 + soff);
            GLD16(gB + (size_t)c * 32 * K, Bs + c * 2048 + soff);
        }
        gA += 64; gB += 64;
        __syncthreads();
#pragma unroll
        for (int ks = 0; ks < 2; ks++) {
            const int gsel = ((ks * 4 + lhi) ^ key) * 8;
            s16x8 af[4], bfr[4];
#pragma unroll
            for (int mi = 0; mi < 4; mi++) af[mi]  = *(const s16x8*)(fArow + mi * 16 * 64 + gsel);
#pragma unroll
            for (int ni = 0; ni < 4; ni++) bfr[ni] = *(const s16x8*)(fBrow + ni * 16 * 64 + gsel);
#pragma unroll
            for (int mi = 0; mi < 4; mi++)
#pragma unroll
                for (int ni = 0; ni < 4; ni++)
                    acc[mi][ni] = __builtin_amdgcn_mfma_f32_16x16x32_bf16(
                        af[mi], bfr[ni], acc[mi][ni], 0, 0, 0);
        }
        __syncthreads();
    }

#pragma unroll
    for (int ni = 0; ni < 4; ni++) {
        const int col = bn + wc * 64 + ni * 16 + lane15;
        if (col >= Nout) continue;
        const float bv = BIAS ? bias[col] : 0.0f;
#pragma unroll
        for (int mi = 0; mi < 4; mi++) {
#pragma unroll
            for (int r = 0; r < 4; r++) {
                const int row = bm + wr * 64 + mi * 16 + lhi * 4 + r;
                float v = acc[mi][ni][r] + bv;
                if (ACT == 1) v = silu_f(v);
                if (ACT == 2) v = (v > 20.0f) ? v : log1pf(__expf(v));
                if (OUT == 1) ((u16*)Cout)[(size_t)row * Nout + col] = f2b(v);
                if (OUT == 2) atomicAdd(&((float*)Cout)[(size_t)row * Nout + col], v);
                if (OUT == 3) ((float*)Cout)[((size_t)blockIdx.z * M + row) * Nout + col] = v;
            }
        }
    }
}

// ---------- classifier layer 1: split-K MFMA, reg-prefetch pipeline + swizzle ----------
// f32 A/W streamed via regs (130 MB W read once). Per iter: write(k) from regs,
// issue loads(k+1) (stay in flight across the lgkmcnt(0)-only barrier -- R8's
// empirically race-clean pattern), MFMA. 4-way-swizzled LDS granules
// (write slot g^(row&3), read slot lhi^(lane15&3)).
#define KCH 512
__global__ __launch_bounds__(256) void gemm_cls_mfma(
    const float* __restrict__ A, const float* __restrict__ W,
    float* __restrict__ C)
{
    __shared__ __align__(16) u16 As[128 * 32];
    __shared__ __align__(16) u16 Bs[128 * 32];
    const int tid = threadIdx.x;
    const int l = tid & 63, w = tid >> 6;
    const int bn = blockIdx.x * 128;
    const int k0 = blockIdx.y * KCH;

    const int sr  = l >> 2;                 // 0..15
    const int sgl = l & 3;                  // source granule (8 f32 / 16 bf16... 8 elems)
    const int row = w * 16 + sr;            // 0..63
    const int skw = ((sgl ^ (sr & 3))) * 8; // swizzled write slot (key = row&3 = sr&3)
    const float* gA0 = A + (size_t)row * KCLS + k0 + sgl * 8;
    const float* gA1 = gA0 + (size_t)64 * KCLS;
    const float* gB0 = W + (size_t)(bn + row) * KCLS + k0 + sgl * 8;
    const float* gB1 = gB0 + (size_t)64 * KCLS;
    u16* lA0 = As + row * 32 + skw;  u16* lA1 = lA0 + 64 * 32;
    u16* lB0 = Bs + row * 32 + skw;  u16* lB1 = lB0 + 64 * 32;

    const int lane15 = l & 15, lhi = l >> 4;
    const int wr = w >> 1, wc = w & 1;
    const int rsel = (lhi ^ (lane15 & 3)) * 8;            // swizzled read slot
    const u16* fA = As + (wr * 64 + lane15) * 32 + rsel;
    const u16* fB = Bs + (wc * 64 + lane15) * 32 + rsel;

    f32x4 acc[4][4] = {};

    // preload iteration 0
    float4 a00 = *(const float4*)(gA0);  float4 a01 = *(const float4*)(gA0 + 4);
    float4 a10 = *(const float4*)(gA1);  float4 a11 = *(const float4*)(gA1 + 4);
    float4 b00 = *(const float4*)(gB0);  float4 b01 = *(const float4*)(gB0 + 4);
    float4 b10 = *(const float4*)(gB1);  float4 b11 = *(const float4*)(gB1 + 4);

    for (int ks = 0; ks < KCH / 32; ks++) {
        if (ks) {
            asm volatile("" ::: "memory");
            __builtin_amdgcn_s_barrier();           // prev iter's LDS reads done
            asm volatile("" ::: "memory");
        }
        uint4 r;
        r.x = pack2(a00.x, a00.y); r.y = pack2(a00.z, a00.w);
        r.z = pack2(a01.x, a01.y); r.w = pack2(a01.z, a01.w);
        *(uint4*)lA0 = r;
        r.x = pack2(a10.x, a10.y); r.y = pack2(a10.z, a10.w);
        r.z = pack2(a11.x, a11.y); r.w = pack2(a11.z, a11.w);
        *(uint4*)lA1 = r;
        r.x = pack2(b00.x, b00.y); r.y = pack2(b00.z, b00.w);
        r.z = pack2(b01.x, b01.y); r.w = pack2(b01.z, b01.w);
        *(uint4*)lB0 = r;
        r.x = pack2(b10.x, b10.y); r.y = pack2(b10.z, b10.w);
        r.z = pack2(b11.x, b11.y); r.w = pack2(b11.z, b11.w);
        *(uint4*)lB1 = r;
        if (ks + 1 < KCH / 32) {                    // prefetch next (overlaps barrier+MFMA)
            gA0 += 32; gA1 += 32; gB0 += 32; gB1 += 32;
            a00 = *(const float4*)(gA0);  a01 = *(const float4*)(gA0 + 4);
            a10 = *(const float4*)(gA1);  a11 = *(const float4*)(gA1 + 4);
            b00 = *(const float4*)(gB0);  b01 = *(const float4*)(gB0 + 4);
            b10 = *(const float4*)(gB1);  b11 = *(const float4*)(gB1 + 4);
        }
        asm volatile("s_waitcnt lgkmcnt(0)" ::: "memory");  // ds_writes visible (loads stay in flight)
        __builtin_amdgcn_s_barrier();
        asm volatile("" ::: "memory");
        s16x8 af[4], bfr[4];
#pragma unroll
        for (int mi = 0; mi < 4; mi++) af[mi]  = *(const s16x8*)(fA + mi * 16 * 32);
#pragma unroll
        for (int ni = 0; ni < 4; ni++) bfr[ni] = *(const s16x8*)(fB + ni * 16 * 32);
#pragma unroll
        for (int mi = 0; mi < 4; mi++)
#pragma unroll
            for (int ni = 0; ni < 4; ni++)
                acc[mi][ni] = __builtin_amdgcn_mfma_f32_16x16x32_bf16(
                    af[mi], bfr[ni], acc[mi][ni], 0, 0, 0);
    }

#pragma unroll
    for (int ni = 0; ni < 4; ni++) {
        const int col = bn + wc * 64 + ni * 16 + lane15;
#pragma unroll
        for (int mi = 0; mi < 4; mi++) {
#pragma unroll
            for (int r = 0; r < 4; r++) {
                const int m = wr * 64 + mi * 16 + lhi * 4 + r;
                atomicAdd(&C[(size_t)m * 1024 + col], acc[mi][ni][r]);
            }
        }
    }
}

// ------- causal depthwise conv1d (DC=5) + SiLU, vectorized x8 (bf16 in/out) -------
__global__ __launch_bounds__(256) void conv_silu_kernel(const u16* __restrict__ xz,
                                                        const float* __restrict__ cw,
                                                        const float* __restrict__ cb,
                                                        u16* __restrict__ uc)
{
    const int idx = blockIdx.x * 256 + threadIdx.x;   // over ROWS * (DI/8)
    const int d8 = idx & 255;                         // DI/8 = 256
    const int bl = idx >> 8;
    const int l  = bl % L_;
    const int b  = bl / L_;
    const u16* ubase = xz + (size_t)b * L_ * (2 * DI_) + d8 * 8;

    float acc[8];
    const float4 cb0 = ((const float4*)cb)[d8 * 2];
    const float4 cb1 = ((const float4*)cb)[d8 * 2 + 1];
    acc[0] = cb0.x; acc[1] = cb0.y; acc[2] = cb0.z; acc[3] = cb0.w;
    acc[4] = cb1.x; acc[5] = cb1.y; acc[6] = cb1.z; acc[7] = cb1.w;

#pragma unroll
    for (int k = 0; k < DC_; k++) {
        const int ll = l + k - (DC_ - 1);
        if (ll < 0) continue;
        const uint4 uv = *(const uint4*)(ubase + (size_t)ll * (2 * DI_));
        const uint32_t uw[4] = {uv.x, uv.y, uv.z, uv.w};
#pragma unroll
        for (int j = 0; j < 8; j++) {
            const float x = b2f((u16)(uw[j >> 1] >> ((j & 1) * 16)));
            acc[j] = fmaf(x, cw[(d8 * 8 + j) * DC_ + k], acc[j]);
        }
    }
    uint4 r;
    r.x = pack2(silu_f(acc[0]), silu_f(acc[1]));
    r.y = pack2(silu_f(acc[2]), silu_f(acc[3]));
    r.z = pack2(silu_f(acc[4]), silu_f(acc[5]));
    r.w = pack2(silu_f(acc[6]), silu_f(acc[7]));
    *(uint4*)(uc + (size_t)bl * DI_ + d8 * 8) = r;
}

// ---------------- extract xdbl[:, 0:64] -> bf16 (dt_proj A operand) ----------------
__global__ __launch_bounds__(256) void dtext_kernel(const float* __restrict__ xdbl,
                                                    u16* __restrict__ dtb)
{
    const int idx = blockIdx.x * 256 + threadIdx.x;   // over ROWS*16
    const int row = idx >> 4, c4 = (idx & 15) * 4;
    float4 v = *(const float4*)(xdbl + (size_t)row * 96 + c4);
    uint2 r;
    r.x = pack2(v.x, v.y); r.y = pack2(v.z, v.w);
    *(uint2*)(dtb + (size_t)row * 64 + c4) = r;
}

// ---------------- selective scan: one thread per (b, d), DS=16 states in regs ----------------
__global__ __launch_bounds__(256) void scan_kernel(const u16* __restrict__ dt,
                                                   const u16* __restrict__ uc,
                                                   const u16* __restrict__ xz,
                                                   const float* __restrict__ xdbl,
                                                   const float* __restrict__ A_log,
                                                   const float* __restrict__ D_ssm,
                                                   u16* __restrict__ y)
{
    const int idx = blockIdx.x * 256 + threadIdx.x;   // over B*DI
    const int d = idx & (DI_ - 1);
    const int b = idx >> 11;
    float A[DS_];
#pragma unroll
    for (int s = 0; s < DS_; s++) A[s] = -__expf(A_log[d * DS_ + s]);
    const float Dv = D_ssm[d];
    float h[DS_] = {};
    for (int l = 0; l < L_; l++) {
        const size_t bl = (size_t)b * L_ + l;
        const float dtv = b2f(dt[bl * DI_ + d]);
        const float uv  = b2f(uc[bl * DI_ + d]);
        const float zv  = b2f(xz[bl * (2 * DI_) + DI_ + d]);
        const float* Bp = xdbl + bl * (DTR_ + 2 * DS_) + DTR_;
        const float* Cp = Bp + DS_;
        float yv = 0.f;
#pragma unroll
        for (int s = 0; s < DS_; s++) {
            h[s] = fmaf(h[s], __expf(dtv * A[s]), dtv * Bp[s] * uv);
            yv = fmaf(h[s], Cp[s], yv);
        }
        yv = fmaf(uv, Dv, yv);
        yv *= silu_f(zv);
        y[bl * DI_ + d] = f2b(yv);
    }
}

// ---------------- classifier layer 2 ----------------
__global__ __launch_bounds__(256) void cls2_kernel(const float* __restrict__ c,
                                                   const float* __restrict__ b1,
                                                   const float* __restrict__ W2,
                                                   const float* __restrict__ b2,
                                                   float* __restrict__ out)
{
    const int b = blockIdx.x;
    float s = 0.f;
    for (int n = threadIdx.x; n < D_; n += 256) {
        float v = c[b * D_ + n] + b1[n];
        v = silu_f(v);
        s = fmaf(v, W2[n], s);
    }
#pragma unroll
    for (int o = 32; o > 0; o >>= 1) s += __shfl_down(s, o, 64);
    __shared__ float red[4];
    const int wid = threadIdx.x >> 6;
    if ((threadIdx.x & 63) == 0) red[wid] = s;
    __syncthreads();
    if (threadIdx.x == 0) out[b] = red[0] + red[1] + red[2] + red[3] + b2[0];
}

extern "C" void kernel_launch(void* const* d_in, const int* in_sizes, int n_in,
                              void* d_out, int out_size, void* d_ws, size_t ws_size,
                              hipStream_t stream)
{
    const float* x         = (const float*)d_in[0];
    const float* n1w       = (const float*)d_in[1];
    const float* n1b       = (const float*)d_in[2];
    const float* in_projW  = (const float*)d_in[3];
    const float* conv_w    = (const float*)d_in[4];
    const float* conv_b    = (const float*)d_in[5];
    const float* x_projW   = (const float*)d_in[6];
    const float* dt_projW  = (const float*)d_in[7];
    const float* dt_projb  = (const float*)d_in[8];
    const float* A_log     = (const float*)d_in[9];
    const float* D_ssm     = (const float*)d_in[10];
    const float* out_projW = (const float*)d_in[11];
    const float* n2w       = (const float*)d_in[12];
    const float* n2b       = (const float*)d_in[13];
    const float* ffn_W1    = (const float*)d_in[14];
    const float* ffn_b1    = (const float*)d_in[15];
    const float* ffn_W2    = (const float*)d_in[16];
    const float* ffn_b2    = (const float*)d_in[17];
    const float* cls_W1    = (const float*)d_in[18];
    const float* cls_b1    = (const float*)d_in[19];
    const float* cls_W2    = (const float*)d_in[20];
    const float* cls_b2    = (const float*)d_in[21];

    // ---- workspace layout ----
    u16* base   = (u16*)d_ws;
    u16* xz_b   = base;                               // ROWS*4096
    u16* uc_b   = xz_b + (size_t)ROWS * 4096;         // ROWS*2048
    u16* dt_b   = uc_b + (size_t)ROWS * 2048;         // ROWS*2048
    u16* y_b    = dt_b + (size_t)ROWS * 2048;         // ROWS*2048
    u16* h_b    = y_b + (size_t)ROWS * 2048;          // ROWS*1024
    float* x2   = (float*)(h_b + (size_t)ROWS * 1024);// ROWS*1024 f32
    float* xdbl = x2 + (size_t)ROWS * 1024;           // ROWS*96 f32
    u16* dtb    = (u16*)(xdbl + (size_t)ROWS * 96);   // ROWS*64
    u16* wbuf   = dtb + (size_t)ROWS * 64;            // WTOT
    float* clsh = (float*)(wbuf + (size_t)WTOT);      // 128*1024 f32
    float* pq   = clsh + (size_t)B_ * D_;             // 2 * ROWS*1024 f32 (split-K partials)

    float* outv = (float*)d_out;    // (B,1)
    float* x3   = outv + B_;        // (B,L,D)

    // 0. all weight conversions
    f2b_all_kernel<<<dim3(5312), dim3(256), 0, stream>>>(
        in_projW, out_projW, ffn_W1, ffn_W2, x_projW, dt_projW, wbuf);
    // 1. LN1 -> bf16
    ln_kernel<<<dim3(ROWS), dim3(256), 0, stream>>>(x, n1w, n1b, h_b);
    // 2. in_proj (BK=64 swz) -> bf16 xz   (3968 x 4096, K=1024), 992 blocks
    gemm128_bk64<0, false, 1><<<dim3(32, 31, 1), dim3(256), 0, stream>>>(
        h_b, wbuf + W_IN, nullptr, xz_b, ROWS, D_, 2 * DI_, D_);
    // 3. causal conv + SiLU (vectorized x8) -> bf16
    conv_silu_kernel<<<dim3(ROWS), dim3(256), 0, stream>>>(xz_b, conv_w, conv_b, uc_b);
    // 4. x_proj (BK=64 swz, split-K x16, atomic f32): xdbl = uc @ x_proj_W^T  (3968 x 96)
    hipMemsetAsync(xdbl, 0, (size_t)ROWS * 96 * sizeof(float), stream);
    gemm128_bk64<0, false, 2><<<dim3(1, 31, 16), dim3(256), 0, stream>>>(
        uc_b, wbuf + W_XP, nullptr, xdbl, ROWS, DI_, DTR_ + 2 * DS_, 128);
    // 5. dt_proj (BK=64 swz, softplus) -> bf16   (3968 x 2048, K=64)
    dtext_kernel<<<dim3(ROWS * 16 / 256), dim3(256), 0, stream>>>(xdbl, dtb);
    gemm128_bk64<2, true, 1><<<dim3(16, 31, 1), dim3(256), 0, stream>>>(
        dtb, wbuf + W_DT, dt_projb, dt_b, ROWS, DTR_, DI_, DTR_);
    // 6. selective scan (+ skip + gate) -> bf16 y
    scan_kernel<<<dim3(B_ * DI_ / 256), dim3(256), 0, stream>>>(
        dt_b, uc_b, xz_b, xdbl, A_log, D_ssm, y_b);
    // 7. out_proj (BK=64 swz, split-K z=2) -> partials p0,p1   (3968 x 1024, K=2048)
    gemm128_bk64<0, false, 3><<<dim3(8, 31, 2), dim3(256), 0, stream>>>(
        y_b, wbuf + W_OUT, nullptr, pq, ROWS, DI_, D_, 1024);
    // 8. fused combine + LN2: x2 = x + p0 + p1, h2 = LN(x2) -> bf16
    ln2_fuse_kernel<<<dim3(ROWS), dim3(256), 0, stream>>>(
        x, pq, pq + (size_t)ROWS * D_, n2w, n2b, x2, h_b);
    // 9. ffn1 (BK=64 swz) + bias + SiLU -> bf16   (3968 x 2048, K=1024), 496 blocks
    gemm128_bk64<1, true, 1><<<dim3(16, 31, 1), dim3(256), 0, stream>>>(
        h_b, wbuf + W_F1, ffn_b1, uc_b, ROWS, D_, 2 * D_, D_);
    // 10. ffn2 (BK=64 swz, split-K z=2) -> partials q0,q1   (3968 x 1024, K=2048)
    gemm128_bk64<0, false, 3><<<dim3(8, 31, 2), dim3(256), 0, stream>>>(
        uc_b, wbuf + W_F2, nullptr, pq, ROWS, 2 * D_, D_, 1024);
    // 11. combine: x3 = x2 + q0 + q1 + b2 -> d_out
    add3_bias_kernel<<<dim3(ROWS * D_ / 4 / 256), dim3(256), 0, stream>>>(
        x2, pq, pq + (size_t)ROWS * D_, ffn_b2, x3);
    // 12. classifier layer 1: split-K MFMA, reg-prefetch pipeline + swizzle
    hipMemsetAsync(clsh, 0, (size_t)B_ * D_ * sizeof(float), stream);
    gemm_cls_mfma<<<dim3(1024 / 128, KCLS / KCH), dim3(256), 0, stream>>>(x3, cls_W1, clsh);
    // 13. classifier layer 2
    cls2_kernel<<<dim3(B_), dim3(256), 0, stream>>>(clsh, cls_b1, cls_W2, cls_b2, outv);
}

// Round 11
// 396.500 us; speedup vs baseline: 1.1023x; 1.1023x over previous
//
#include <hip/hip_runtime.h>
#include <cstddef>
#include <cstdint>

#define B_   128
#define L_   31
#define D_   1024
#define DI_  2048
#define DS_  16
#define DC_  5
#define DTR_ 64
#define ROWS (B_ * L_)   // 3968
#define KCLS (L_ * D_)   // 31744

// weight-buffer offsets (u16 elements)
#define W_IN  0          // 4096x1024
#define W_OUT 4194304    // 1024x2048
#define W_F1  6291456    // 2048x1024
#define W_F2  8388608    // 1024x2048
#define W_XP  10485760   // 128x2048 (rows 96..127 zero)
#define W_DT  10747904   // 2048x64
#define WTOT  10878976

typedef unsigned short u16;
typedef __attribute__((ext_vector_type(8))) short s16x8;
typedef __attribute__((ext_vector_type(4))) float f32x4;

__device__ __forceinline__ float silu_f(float x) { return x / (1.0f + __expf(-x)); }

__device__ __forceinline__ u16 f2b(float f) {
    union { float f; uint32_t u; } c; c.f = f;
    uint32_t u = c.u + 0x7FFF + ((c.u >> 16) & 1);
    return (u16)(u >> 16);
}
__device__ __forceinline__ float b2f(u16 b) {
    union { uint32_t u; float f; } c; c.u = ((uint32_t)b) << 16;
    return c.f;
}
__device__ __forceinline__ uint32_t pack2(float lo, float hi) {
    return (uint32_t)f2b(lo) | ((uint32_t)f2b(hi) << 16);
}
__device__ __forceinline__ void cvt8(const float* __restrict__ s, u16* __restrict__ d) {
    const float4* p = (const float4*)s;
    float4 a = p[0], b = p[1];
    uint4 r;
    r.x = pack2(a.x, a.y); r.y = pack2(a.z, a.w);
    r.z = pack2(b.x, b.y); r.w = pack2(b.z, b.w);
    *(uint4*)d = r;
}

#define GLD16(g, s) __builtin_amdgcn_global_load_lds( \
    (const __attribute__((address_space(1))) void*)(g), \
    (__attribute__((address_space(3))) void*)(s), 16, 0, 0)

// ---------------- all-weights fp32 -> bf16 (single launch) ----------------
__global__ __launch_bounds__(256) void f2b_all_kernel(
    const float* __restrict__ inW, const float* __restrict__ outW,
    const float* __restrict__ f1W, const float* __restrict__ f2W,
    const float* __restrict__ xpW, const float* __restrict__ dtW,
    u16* __restrict__ wbuf)
{
    int g = blockIdx.x * 256 + threadIdx.x;
    if (g < 524288) { cvt8(inW + (size_t)g * 8, wbuf + W_IN + (size_t)g * 8); return; }
    g -= 524288;
    if (g < 262144) { cvt8(outW + (size_t)g * 8, wbuf + W_OUT + (size_t)g * 8); return; }
    g -= 262144;
    if (g < 262144) { cvt8(f1W + (size_t)g * 8, wbuf + W_F1 + (size_t)g * 8); return; }
    g -= 262144;
    if (g < 262144) { cvt8(f2W + (size_t)g * 8, wbuf + W_F2 + (size_t)g * 8); return; }
    g -= 262144;
    if (g < 32768) {   // x_proj, padded 96 -> 128 rows
        const int row = g >> 8, col8 = (g & 255) * 8;
        u16* d = wbuf + W_XP + (size_t)row * 2048 + col8;
        if (row < 96) cvt8(xpW + (size_t)row * 2048 + col8, d);
        else *(uint4*)d = make_uint4(0, 0, 0, 0);
        return;
    }
    g -= 32768;
    if (g < 16384) cvt8(dtW + (size_t)g * 8, wbuf + W_DT + (size_t)g * 8);
}

// ---------------- LayerNorm (one block per row, D=1024) -> bf16 out ----------------
__global__ __launch_bounds__(256) void ln_kernel(const float* __restrict__ x,
                                                 const float* __restrict__ w,
                                                 const float* __restrict__ b,
                                                 u16* __restrict__ y)
{
    const int row = blockIdx.x;
    const float* xr = x + (size_t)row * D_;
    float v[4];
    float sum = 0.f, sq = 0.f;
#pragma unroll
    for (int i = 0; i < 4; i++) {
        v[i] = xr[threadIdx.x + i * 256];
        sum += v[i];
        sq  += v[i] * v[i];
    }
#pragma unroll
    for (int o = 32; o > 0; o >>= 1) {
        sum += __shfl_down(sum, o, 64);
        sq  += __shfl_down(sq, o, 64);
    }
    __shared__ float red[8];
    const int wid = threadIdx.x >> 6;
    if ((threadIdx.x & 63) == 0) { red[wid] = sum; red[4 + wid] = sq; }
    __syncthreads();
    sum = red[0] + red[1] + red[2] + red[3];
    sq  = red[4] + red[5] + red[6] + red[7];
    const float mean = sum * (1.0f / D_);
    const float var  = sq * (1.0f / D_) - mean * mean;
    const float rstd = rsqrtf(var + 1e-5f);
    u16* yr = y + (size_t)row * D_;
#pragma unroll
    for (int i = 0; i < 4; i++) {
        const int c = threadIdx.x + i * 256;
        yr[c] = f2b((v[i] - mean) * rstd * w[c] + b[c]);
    }
}

// ---------------- fused: x2 = x + p0 + p1; h2 = LN(x2) -> bf16 ----------------
__global__ __launch_bounds__(256) void ln2_fuse_kernel(const float* __restrict__ x,
                                                       const float* __restrict__ p0,
                                                       const float* __restrict__ p1,
                                                       const float* __restrict__ w,
                                                       const float* __restrict__ b,
                                                       float* __restrict__ x2,
                                                       u16* __restrict__ y)
{
    const int row = blockIdx.x;
    const size_t base = (size_t)row * D_;
    float v[4];
    float sum = 0.f, sq = 0.f;
#pragma unroll
    for (int i = 0; i < 4; i++) {
        const int c = threadIdx.x + i * 256;
        const float s = x[base + c] + p0[base + c] + p1[base + c];
        x2[base + c] = s;
        v[i] = s;
        sum += s;
        sq  += s * s;
    }
#pragma unroll
    for (int o = 32; o > 0; o >>= 1) {
        sum += __shfl_down(sum, o, 64);
        sq  += __shfl_down(sq, o, 64);
    }
    __shared__ float red[8];
    const int wid = threadIdx.x >> 6;
    if ((threadIdx.x & 63) == 0) { red[wid] = sum; red[4 + wid] = sq; }
    __syncthreads();
    sum = red[0] + red[1] + red[2] + red[3];
    sq  = red[4] + red[5] + red[6] + red[7];
    const float mean = sum * (1.0f / D_);
    const float var  = sq * (1.0f / D_) - mean * mean;
    const float rstd = rsqrtf(var + 1e-5f);
    u16* yr = y + base;
#pragma unroll
    for (int i = 0; i < 4; i++) {
        const int c = threadIdx.x + i * 256;
        yr[c] = f2b((v[i] - mean) * rstd * w[c] + b[c]);
    }
}

// ---------------- x3 = x2 + q0 + q1 + b2 (vectorized) ----------------
__global__ __launch_bounds__(256) void add3_bias_kernel(const float* __restrict__ x2,
                                                        const float* __restrict__ q0,
                                                        const float* __restrict__ q1,
                                                        const float* __restrict__ b2,
                                                        float* __restrict__ x3)
{
    const int i = blockIdx.x * 256 + threadIdx.x;   // float4 index over ROWS*1024/4
    float4 a  = ((const float4*)x2)[i];
    float4 c0 = ((const float4*)q0)[i];
    float4 c1 = ((const float4*)q1)[i];
    float4 bb = ((const float4*)b2)[i & 255];
    float4 r;
    r.x = a.x + c0.x + c1.x + bb.x;
    r.y = a.y + c0.y + c1.y + bb.y;
    r.z = a.z + c0.z + c1.z + bb.z;
    r.w = a.w + c0.w + c1.w + bb.w;
    ((float4*)x3)[i] = r;
}

// ======== 128x128-tile bf16 MFMA GEMM, BK=64, 4 waves, XOR-swizzled LDS ========
// R9-proven: m97 2-barrier skeleton, BK=64 (half the barrier drains, 32 KB LDS
// keeps ~4 blocks/CU), both-sides swizzle (source granule sg^(srow&7), read
// granule (ks*4+lhi)^(lane15&7)) -> 2-way max bank aliasing (free, m136).
// ACT: 0 none, 1 silu, 2 softplus. OUT: 1 bf16, 2 f32 atomicAdd, 3 f32 partial.
template <int ACT, bool BIAS, int OUT>
__global__ __launch_bounds__(256) void gemm128_bk64(
    const u16* __restrict__ A, const u16* __restrict__ W,
    const float* __restrict__ bias, void* __restrict__ Cout,
    int M, int K, int Nout, int kLen)
{
    __shared__ __align__(16) u16 As[128 * 64];   // 16 KB
    __shared__ __align__(16) u16 Bs[128 * 64];   // 16 KB
    const int tid = threadIdx.x;
    const int l = tid & 63, w = tid >> 6;
    const int bm = blockIdx.y * 128, bn = blockIdx.x * 128;
    const int kOff = blockIdx.z * kLen;

    const int srow = tid >> 3;                   // 0..31
    const int sg   = tid & 7;                    // LDS granule slot (linear)
    const int sgx  = sg ^ (srow & 7);            // swizzled SOURCE granule
    const u16* gA = A + (size_t)(bm + srow) * K + kOff + sgx * 8;
    const u16* gB = W + (size_t)(bn + srow) * K + kOff + sgx * 8;
    const int soff = srow * 64 + sg * 8;         // == tid*8 (lane-linear)

    const int lane15 = l & 15, lhi = l >> 4;
    const int key = lane15 & 7;
    const int wr = w >> 1, wc = w & 1;
    const u16* fArow = As + (wr * 64 + lane15) * 64;
    const u16* fBrow = Bs + (wc * 64 + lane15) * 64;

    f32x4 acc[4][4] = {};

    for (int kk = 0; kk < kLen; kk += 64) {
#pragma unroll
        for (int c = 0; c < 4; c++) {
            GLD16(gA + (size_t)c * 32 * K, As + c * 2048 + soff);
            GLD16(gB + (size_t)c * 32 * K, Bs + c * 2048 + soff);
        }
        gA += 64; gB += 64;
        __syncthreads();
#pragma unroll
        for (int ks = 0; ks < 2; ks++) {
            const int gsel = ((ks * 4 + lhi) ^ key) * 8;
            s16x8 af[4], bfr[4];
#pragma unroll
            for (int mi = 0; mi < 4; mi++) af[mi]  = *(const s16x8*)(fArow + mi * 16 * 64 + gsel);
#pragma unroll
            for (int ni = 0; ni < 4; ni++) bfr[ni] = *(const s16x8*)(fBrow + ni * 16 * 64 + gsel);
#pragma unroll
            for (int mi = 0; mi < 4; mi++)
#pragma unroll
                for (int ni = 0; ni < 4; ni++)
                    acc[mi][ni] = __builtin_amdgcn_mfma_f32_16x16x32_bf16(
                        af[mi], bfr[ni], acc[mi][ni], 0, 0, 0);
        }
        __syncthreads();
    }

#pragma unroll
    for (int ni = 0; ni < 4; ni++) {
        const int col = bn + wc * 64 + ni * 16 + lane15;
        if (col >= Nout) continue;
        const float bv = BIAS ? bias[col] : 0.0f;
#pragma unroll
        for (int mi = 0; mi < 4; mi++) {
#pragma unroll
            for (int r = 0; r < 4; r++) {
                const int row = bm + wr * 64 + mi * 16 + lhi * 4 + r;
                float v = acc[mi][ni][r] + bv;
                if (ACT == 1) v = silu_f(v);
                if (ACT == 2) v = (v > 20.0f) ? v : log1pf(__expf(v));
                if (OUT == 1) ((u16*)Cout)[(size_t)row * Nout + col] = f2b(v);
                if (OUT == 2) atomicAdd(&((float*)Cout)[(size_t)row * Nout + col], v);
                if (OUT == 3) ((float*)Cout)[((size_t)blockIdx.z * M + row) * Nout + col] = v;
            }
        }
    }
}

// ---------- classifier layer 1: split-K MFMA, reg-prefetch pipeline + swizzle ----------
#define KCH 512
__global__ __launch_bounds__(256) void gemm_cls_mfma(
    const float* __restrict__ A, const float* __restrict__ W,
    float* __restrict__ C)
{
    __shared__ __align__(16) u16 As[128 * 32];
    __shared__ __align__(16) u16 Bs[128 * 32];
    const int tid = threadIdx.x;
    const int l = tid & 63, w = tid >> 6;
    const int bn = blockIdx.x * 128;
    const int k0 = blockIdx.y * KCH;

    const int sr  = l >> 2;                 // 0..15
    const int sgl = l & 3;                  // source granule
    const int row = w * 16 + sr;            // 0..63
    const int skw = ((sgl ^ (sr & 3))) * 8; // swizzled write slot (key = row&3)
    const float* gA0 = A + (size_t)row * KCLS + k0 + sgl * 8;
    const float* gA1 = gA0 + (size_t)64 * KCLS;
    const float* gB0 = W + (size_t)(bn + row) * KCLS + k0 + sgl * 8;
    const float* gB1 = gB0 + (size_t)64 * KCLS;
    u16* lA0 = As + row * 32 + skw;  u16* lA1 = lA0 + 64 * 32;
    u16* lB0 = Bs + row * 32 + skw;  u16* lB1 = lB0 + 64 * 32;

    const int lane15 = l & 15, lhi = l >> 4;
    const int wr = w >> 1, wc = w & 1;
    const int rsel = (lhi ^ (lane15 & 3)) * 8;            // swizzled read slot
    const u16* fA = As + (wr * 64 + lane15) * 32 + rsel;
    const u16* fB = Bs + (wc * 64 + lane15) * 32 + rsel;

    f32x4 acc[4][4] = {};

    float4 a00 = *(const float4*)(gA0);  float4 a01 = *(const float4*)(gA0 + 4);
    float4 a10 = *(const float4*)(gA1);  float4 a11 = *(const float4*)(gA1 + 4);
    float4 b00 = *(const float4*)(gB0);  float4 b01 = *(const float4*)(gB0 + 4);
    float4 b10 = *(const float4*)(gB1);  float4 b11 = *(const float4*)(gB1 + 4);

    for (int ks = 0; ks < KCH / 32; ks++) {
        if (ks) {
            asm volatile("" ::: "memory");
            __builtin_amdgcn_s_barrier();           // prev iter's LDS reads done
            asm volatile("" ::: "memory");
        }
        uint4 r;
        r.x = pack2(a00.x, a00.y); r.y = pack2(a00.z, a00.w);
        r.z = pack2(a01.x, a01.y); r.w = pack2(a01.z, a01.w);
        *(uint4*)lA0 = r;
        r.x = pack2(a10.x, a10.y); r.y = pack2(a10.z, a10.w);
        r.z = pack2(a11.x, a11.y); r.w = pack2(a11.z, a11.w);
        *(uint4*)lA1 = r;
        r.x = pack2(b00.x, b00.y); r.y = pack2(b00.z, b00.w);
        r.z = pack2(b01.x, b01.y); r.w = pack2(b01.z, b01.w);
        *(uint4*)lB0 = r;
        r.x = pack2(b10.x, b10.y); r.y = pack2(b10.z, b10.w);
        r.z = pack2(b11.x, b11.y); r.w = pack2(b11.z, b11.w);
        *(uint4*)lB1 = r;
        if (ks + 1 < KCH / 32) {                    // prefetch next (overlaps barrier+MFMA)
            gA0 += 32; gA1 += 32; gB0 += 32; gB1 += 32;
            a00 = *(const float4*)(gA0);  a01 = *(const float4*)(gA0 + 4);
            a10 = *(const float4*)(gA1);  a11 = *(const float4*)(gA1 + 4);
            b00 = *(const float4*)(gB0);  b01 = *(const float4*)(gB0 + 4);
            b10 = *(const float4*)(gB1);  b11 = *(const float4*)(gB1 + 4);
        }
        asm volatile("s_waitcnt lgkmcnt(0)" ::: "memory");  // ds_writes visible (loads in flight)
        __builtin_amdgcn_s_barrier();
        asm volatile("" ::: "memory");
        s16x8 af[4], bfr[4];
#pragma unroll
        for (int mi = 0; mi < 4; mi++) af[mi]  = *(const s16x8*)(fA + mi * 16 * 32);
#pragma unroll
        for (int ni = 0; ni < 4; ni++) bfr[ni] = *(const s16x8*)(fB + ni * 16 * 32);
#pragma unroll
        for (int mi = 0; mi < 4; mi++)
#pragma unroll
            for (int ni = 0; ni < 4; ni++)
                acc[mi][ni] = __builtin_amdgcn_mfma_f32_16x16x32_bf16(
                    af[mi], bfr[ni], acc[mi][ni], 0, 0, 0);
    }

#pragma unroll
    for (int ni = 0; ni < 4; ni++) {
        const int col = bn + wc * 64 + ni * 16 + lane15;
#pragma unroll
        for (int mi = 0; mi < 4; mi++) {
#pragma unroll
            for (int r = 0; r < 4; r++) {
                const int m = wr * 64 + mi * 16 + lhi * 4 + r;
                atomicAdd(&C[(size_t)m * 1024 + col], acc[mi][ni][r]);
            }
        }
    }
}

// ------- causal conv1d (DC=5) + SiLU: vectorized data path + LDS-staged weights -------
// One block per (b,l) row; thread t handles 8 channels d = t*8..t*8+7.
// cw (2048x5 f32 = 40 KB) + cb (8 KB) staged to LDS via coalesced float4 loads
// once per block; data loads are uint4 (16B/lane, coalesced). No fragmented
// global scalar loads (R10's 76 us pathology).
__global__ __launch_bounds__(256) void conv_silu_kernel(const u16* __restrict__ xz,
                                                        const float* __restrict__ cw,
                                                        const float* __restrict__ cb,
                                                        u16* __restrict__ uc)
{
    __shared__ float cws[DI_ * DC_];   // 40 KB
    __shared__ float cbs[DI_];         // 8 KB
    // coalesced stage: 10240 + 2048 float4-quads = 2560 + 512 float4
    for (int i = threadIdx.x; i < DI_ * DC_ / 4; i += 256)
        ((float4*)cws)[i] = ((const float4*)cw)[i];
    for (int i = threadIdx.x; i < DI_ / 4; i += 256)
        ((float4*)cbs)[i] = ((const float4*)cb)[i];
    __syncthreads();

    const int bl = blockIdx.x;
    const int l  = bl % L_;
    const int b  = bl / L_;
    const int d0 = threadIdx.x * 8;
    const u16* ubase = xz + (size_t)b * L_ * (2 * DI_) + d0;

    float acc[8];
#pragma unroll
    for (int j = 0; j < 8; j++) acc[j] = cbs[d0 + j];

#pragma unroll
    for (int k = 0; k < DC_; k++) {
        const int ll = l + k - (DC_ - 1);
        if (ll < 0) continue;
        const uint4 uv = *(const uint4*)(ubase + (size_t)ll * (2 * DI_));
        const uint32_t uw[4] = {uv.x, uv.y, uv.z, uv.w};
#pragma unroll
        for (int j = 0; j < 8; j++) {
            const float x = b2f((u16)(uw[j >> 1] >> ((j & 1) * 16)));
            acc[j] = fmaf(x, cws[(d0 + j) * DC_ + k], acc[j]);
        }
    }
    uint4 r;
    r.x = pack2(silu_f(acc[0]), silu_f(acc[1]));
    r.y = pack2(silu_f(acc[2]), silu_f(acc[3]));
    r.z = pack2(silu_f(acc[4]), silu_f(acc[5]));
    r.w = pack2(silu_f(acc[6]), silu_f(acc[7]));
    *(uint4*)(uc + (size_t)bl * DI_ + d0) = r;
}

// ---------------- extract xdbl[:, 0:64] -> bf16 (dt_proj A operand) ----------------
__global__ __launch_bounds__(256) void dtext_kernel(const float* __restrict__ xdbl,
                                                    u16* __restrict__ dtb)
{
    const int idx = blockIdx.x * 256 + threadIdx.x;   // over ROWS*16
    const int row = idx >> 4, c4 = (idx & 15) * 4;
    float4 v = *(const float4*)(xdbl + (size_t)row * 96 + c4);
    uint2 r;
    r.x = pack2(v.x, v.y); r.y = pack2(v.z, v.w);
    *(uint2*)(dtb + (size_t)row * 64 + c4) = r;
}

// ---------------- selective scan: one thread per (b, d), DS=16 states in regs ----------------
__global__ __launch_bounds__(256) void scan_kernel(const u16* __restrict__ dt,
                                                   const u16* __restrict__ uc,
                                                   const u16* __restrict__ xz,
                                                   const float* __restrict__ xdbl,
                                                   const float* __restrict__ A_log,
                                                   const float* __restrict__ D_ssm,
                                                   u16* __restrict__ y)
{
    const int idx = blockIdx.x * 256 + threadIdx.x;   // over B*DI
    const int d = idx & (DI_ - 1);
    const int b = idx >> 11;
    float A[DS_];
#pragma unroll
    for (int s = 0; s < DS_; s++) A[s] = -__expf(A_log[d * DS_ + s]);
    const float Dv = D_ssm[d];
    float h[DS_] = {};
    for (int l = 0; l < L_; l++) {
        const size_t bl = (size_t)b * L_ + l;
        const float dtv = b2f(dt[bl * DI_ + d]);
        const float uv  = b2f(uc[bl * DI_ + d]);
        const float zv  = b2f(xz[bl * (2 * DI_) + DI_ + d]);
        const float* Bp = xdbl + bl * (DTR_ + 2 * DS_) + DTR_;
        const float* Cp = Bp + DS_;
        float yv = 0.f;
#pragma unroll
        for (int s = 0; s < DS_; s++) {
            h[s] = fmaf(h[s], __expf(dtv * A[s]), dtv * Bp[s] * uv);
            yv = fmaf(h[s], Cp[s], yv);
        }
        yv = fmaf(uv, Dv, yv);
        yv *= silu_f(zv);
        y[bl * DI_ + d] = f2b(yv);
    }
}

// ---------------- classifier layer 2 ----------------
__global__ __launch_bounds__(256) void cls2_kernel(const float* __restrict__ c,
                                                   const float* __restrict__ b1,
                                                   const float* __restrict__ W2,
                                                   const float* __restrict__ b2,
                                                   float* __restrict__ out)
{
    const int b = blockIdx.x;
    float s = 0.f;
    for (int n = threadIdx.x; n < D_; n += 256) {
        float v = c[b * D_ + n] + b1[n];
        v = silu_f(v);
        s = fmaf(v, W2[n], s);
    }
#pragma unroll
    for (int o = 32; o > 0; o >>= 1) s += __shfl_down(s, o, 64);
    __shared__ float red[4];
    const int wid = threadIdx.x >> 6;
    if ((threadIdx.x & 63) == 0) red[wid] = s;
    __syncthreads();
    if (threadIdx.x == 0) out[b] = red[0] + red[1] + red[2] + red[3] + b2[0];
}

extern "C" void kernel_launch(void* const* d_in, const int* in_sizes, int n_in,
                              void* d_out, int out_size, void* d_ws, size_t ws_size,
                              hipStream_t stream)
{
    const float* x         = (const float*)d_in[0];
    const float* n1w       = (const float*)d_in[1];
    const float* n1b       = (const float*)d_in[2];
    const float* in_projW  = (const float*)d_in[3];
    const float* conv_w    = (const float*)d_in[4];
    const float* conv_b    = (const float*)d_in[5];
    const float* x_projW   = (const float*)d_in[6];
    const float* dt_projW  = (const float*)d_in[7];
    const float* dt_projb  = (const float*)d_in[8];
    const float* A_log     = (const float*)d_in[9];
    const float* D_ssm     = (const float*)d_in[10];
    const float* out_projW = (const float*)d_in[11];
    const float* n2w       = (const float*)d_in[12];
    const float* n2b       = (const float*)d_in[13];
    const float* ffn_W1    = (const float*)d_in[14];
    const float* ffn_b1    = (const float*)d_in[15];
    const float* ffn_W2    = (const float*)d_in[16];
    const float* ffn_b2    = (const float*)d_in[17];
    const float* cls_W1    = (const float*)d_in[18];
    const float* cls_b1    = (const float*)d_in[19];
    const float* cls_W2    = (const float*)d_in[20];
    const float* cls_b2    = (const float*)d_in[21];

    // ---- workspace layout ----
    u16* base   = (u16*)d_ws;
    u16* xz_b   = base;                               // ROWS*4096
    u16* uc_b   = xz_b + (size_t)ROWS * 4096;         // ROWS*2048
    u16* dt_b   = uc_b + (size_t)ROWS * 2048;         // ROWS*2048
    u16* y_b    = dt_b + (size_t)ROWS * 2048;         // ROWS*2048
    u16* h_b    = y_b + (size_t)ROWS * 2048;          // ROWS*1024
    float* x2   = (float*)(h_b + (size_t)ROWS * 1024);// ROWS*1024 f32
    float* xdbl = x2 + (size_t)ROWS * 1024;           // ROWS*96 f32
    u16* dtb    = (u16*)(xdbl + (size_t)ROWS * 96);   // ROWS*64
    u16* wbuf   = dtb + (size_t)ROWS * 64;            // WTOT
    float* clsh = (float*)(wbuf + (size_t)WTOT);      // 128*1024 f32
    float* pq   = clsh + (size_t)B_ * D_;             // 2 * ROWS*1024 f32 (split-K partials)

    float* outv = (float*)d_out;    // (B,1)
    float* x3   = outv + B_;        // (B,L,D)

    // 0. all weight conversions
    f2b_all_kernel<<<dim3(5312), dim3(256), 0, stream>>>(
        in_projW, out_projW, ffn_W1, ffn_W2, x_projW, dt_projW, wbuf);
    // 1. LN1 -> bf16
    ln_kernel<<<dim3(ROWS), dim3(256), 0, stream>>>(x, n1w, n1b, h_b);
    // 2. in_proj (BK=64 swz) -> bf16 xz   (3968 x 4096, K=1024), 992 blocks
    gemm128_bk64<0, false, 1><<<dim3(32, 31, 1), dim3(256), 0, stream>>>(
        h_b, wbuf + W_IN, nullptr, xz_b, ROWS, D_, 2 * DI_, D_);
    // 3. causal conv + SiLU (vec data + LDS weights) -> bf16
    conv_silu_kernel<<<dim3(ROWS), dim3(256), 0, stream>>>(xz_b, conv_w, conv_b, uc_b);
    // 4. x_proj (BK=64 swz, split-K x16, atomic f32): xdbl = uc @ x_proj_W^T  (3968 x 96)
    hipMemsetAsync(xdbl, 0, (size_t)ROWS * 96 * sizeof(float), stream);
    gemm128_bk64<0, false, 2><<<dim3(1, 31, 16), dim3(256), 0, stream>>>(
        uc_b, wbuf + W_XP, nullptr, xdbl, ROWS, DI_, DTR_ + 2 * DS_, 128);
    // 5. dt_proj (BK=64 swz, softplus) -> bf16   (3968 x 2048, K=64)
    dtext_kernel<<<dim3(ROWS * 16 / 256), dim3(256), 0, stream>>>(xdbl, dtb);
    gemm128_bk64<2, true, 1><<<dim3(16, 31, 1), dim3(256), 0, stream>>>(
        dtb, wbuf + W_DT, dt_projb, dt_b, ROWS, DTR_, DI_, DTR_);
    // 6. selective scan (+ skip + gate) -> bf16 y
    scan_kernel<<<dim3(B_ * DI_ / 256), dim3(256), 0, stream>>>(
        dt_b, uc_b, xz_b, xdbl, A_log, D_ssm, y_b);
    // 7. out_proj (BK=64 swz, split-K z=2) -> partials p0,p1   (3968 x 1024, K=2048)
    gemm128_bk64<0, false, 3><<<dim3(8, 31, 2), dim3(256), 0, stream>>>(
        y_b, wbuf + W_OUT, nullptr, pq, ROWS, DI_, D_, 1024);
    // 8. fused combine + LN2: x2 = x + p0 + p1, h2 = LN(x2) -> bf16
    ln2_fuse_kernel<<<dim3(ROWS), dim3(256), 0, stream>>>(
        x, pq, pq + (size_t)ROWS * D_, n2w, n2b, x2, h_b);
    // 9. ffn1 (BK=64 swz) + bias + SiLU -> bf16   (3968 x 2048, K=1024), 496 blocks
    gemm128_bk64<1, true, 1><<<dim3(16, 31, 1), dim3(256), 0, stream>>>(
        h_b, wbuf + W_F1, ffn_b1, uc_b, ROWS, D_, 2 * D_, D_);
    // 10. ffn2 (BK=64 swz, split-K z=2) -> partials q0,q1   (3968 x 1024, K=2048)
    gemm128_bk64<0, false, 3><<<dim3(8, 31, 2), dim3(256), 0, stream>>>(
        uc_b, wbuf + W_F2, nullptr, pq, ROWS, 2 * D_, D_, 1024);
    // 11. combine: x3 = x2 + q0 + q1 + b2 -> d_out
    add3_bias_kernel<<<dim3(ROWS * D_ / 4 / 256), dim3(256), 0, stream>>>(
        x2, pq, pq + (size_t)ROWS * D_, ffn_b2, x3);
    // 12. classifier layer 1: split-K MFMA, reg-prefetch pipeline + swizzle
    hipMemsetAsync(clsh, 0, (size_t)B_ * D_ * sizeof(float), stream);
    gemm_cls_mfma<<<dim3(1024 / 128, KCLS / KCH), dim3(256), 0, stream>>>(x3, cls_W1, clsh);
    // 13. classifier layer 2
    cls2_kernel<<<dim3(B_), dim3(256), 0, stream>>>(clsh, cls_b1, cls_W2, cls_b2, outv);
}

// Round 12
// 386.411 us; speedup vs baseline: 1.1311x; 1.0261x over previous
//
#include <hip/hip_runtime.h>
#include <cstddef>
#include <cstdint>

#define B_   128
#define L_   31
#define D_   1024
#define DI_  2048
#define DS_  16
#define DC_  5
#define DTR_ 64
#define ROWS (B_ * L_)   // 3968
#define KCLS (L_ * D_)   // 31744

// weight-buffer offsets (u16 elements)
#define W_IN  0          // 4096x1024
#define W_OUT 4194304    // 1024x2048
#define W_F1  6291456    // 2048x1024
#define W_F2  8388608    // 1024x2048
#define W_XP  10485760   // 128x2048 (rows 96..127 zero)
#define W_DT  10747904   // 2048x64
#define WTOT  10878976

typedef unsigned short u16;
typedef __attribute__((ext_vector_type(8))) short s16x8;
typedef __attribute__((ext_vector_type(4))) float f32x4;

__device__ __forceinline__ float silu_f(float x) { return x / (1.0f + __expf(-x)); }

__device__ __forceinline__ u16 f2b(float f) {
    union { float f; uint32_t u; } c; c.f = f;
    uint32_t u = c.u + 0x7FFF + ((c.u >> 16) & 1);
    return (u16)(u >> 16);
}
__device__ __forceinline__ float b2f(u16 b) {
    union { uint32_t u; float f; } c; c.u = ((uint32_t)b) << 16;
    return c.f;
}
__device__ __forceinline__ uint32_t pack2(float lo, float hi) {
    return (uint32_t)f2b(lo) | ((uint32_t)f2b(hi) << 16);
}
__device__ __forceinline__ void cvt8(const float* __restrict__ s, u16* __restrict__ d) {
    const float4* p = (const float4*)s;
    float4 a = p[0], b = p[1];
    uint4 r;
    r.x = pack2(a.x, a.y); r.y = pack2(a.z, a.w);
    r.z = pack2(b.x, b.y); r.w = pack2(b.z, b.w);
    *(uint4*)d = r;
}

#define GLD16(g, s) __builtin_amdgcn_global_load_lds( \
    (const __attribute__((address_space(1))) void*)(g), \
    (__attribute__((address_space(3))) void*)(s), 16, 0, 0)

// ---------------- all-weights fp32 -> bf16 (single launch) ----------------
__global__ __launch_bounds__(256) void f2b_all_kernel(
    const float* __restrict__ inW, const float* __restrict__ outW,
    const float* __restrict__ f1W, const float* __restrict__ f2W,
    const float* __restrict__ xpW, const float* __restrict__ dtW,
    u16* __restrict__ wbuf)
{
    int g = blockIdx.x * 256 + threadIdx.x;
    if (g < 524288) { cvt8(inW + (size_t)g * 8, wbuf + W_IN + (size_t)g * 8); return; }
    g -= 524288;
    if (g < 262144) { cvt8(outW + (size_t)g * 8, wbuf + W_OUT + (size_t)g * 8); return; }
    g -= 262144;
    if (g < 262144) { cvt8(f1W + (size_t)g * 8, wbuf + W_F1 + (size_t)g * 8); return; }
    g -= 262144;
    if (g < 262144) { cvt8(f2W + (size_t)g * 8, wbuf + W_F2 + (size_t)g * 8); return; }
    g -= 262144;
    if (g < 32768) {   // x_proj, padded 96 -> 128 rows
        const int row = g >> 8, col8 = (g & 255) * 8;
        u16* d = wbuf + W_XP + (size_t)row * 2048 + col8;
        if (row < 96) cvt8(xpW + (size_t)row * 2048 + col8, d);
        else *(uint4*)d = make_uint4(0, 0, 0, 0);
        return;
    }
    g -= 32768;
    if (g < 16384) cvt8(dtW + (size_t)g * 8, wbuf + W_DT + (size_t)g * 8);
}

// ---------------- LayerNorm (one block per row, D=1024) -> bf16 out ----------------
__global__ __launch_bounds__(256) void ln_kernel(const float* __restrict__ x,
                                                 const float* __restrict__ w,
                                                 const float* __restrict__ b,
                                                 u16* __restrict__ y)
{
    const int row = blockIdx.x;
    const float* xr = x + (size_t)row * D_;
    float v[4];
    float sum = 0.f, sq = 0.f;
#pragma unroll
    for (int i = 0; i < 4; i++) {
        v[i] = xr[threadIdx.x + i * 256];
        sum += v[i];
        sq  += v[i] * v[i];
    }
#pragma unroll
    for (int o = 32; o > 0; o >>= 1) {
        sum += __shfl_down(sum, o, 64);
        sq  += __shfl_down(sq, o, 64);
    }
    __shared__ float red[8];
    const int wid = threadIdx.x >> 6;
    if ((threadIdx.x & 63) == 0) { red[wid] = sum; red[4 + wid] = sq; }
    __syncthreads();
    sum = red[0] + red[1] + red[2] + red[3];
    sq  = red[4] + red[5] + red[6] + red[7];
    const float mean = sum * (1.0f / D_);
    const float var  = sq * (1.0f / D_) - mean * mean;
    const float rstd = rsqrtf(var + 1e-5f);
    u16* yr = y + (size_t)row * D_;
#pragma unroll
    for (int i = 0; i < 4; i++) {
        const int c = threadIdx.x + i * 256;
        yr[c] = f2b((v[i] - mean) * rstd * w[c] + b[c]);
    }
}

// ---------------- fused: x2 = x + p0 + p1; h2 = LN(x2) -> bf16 ----------------
__global__ __launch_bounds__(256) void ln2_fuse_kernel(const float* __restrict__ x,
                                                       const float* __restrict__ p0,
                                                       const float* __restrict__ p1,
                                                       const float* __restrict__ w,
                                                       const float* __restrict__ b,
                                                       float* __restrict__ x2,
                                                       u16* __restrict__ y)
{
    const int row = blockIdx.x;
    const size_t base = (size_t)row * D_;
    float v[4];
    float sum = 0.f, sq = 0.f;
#pragma unroll
    for (int i = 0; i < 4; i++) {
        const int c = threadIdx.x + i * 256;
        const float s = x[base + c] + p0[base + c] + p1[base + c];
        x2[base + c] = s;
        v[i] = s;
        sum += s;
        sq  += s * s;
    }
#pragma unroll
    for (int o = 32; o > 0; o >>= 1) {
        sum += __shfl_down(sum, o, 64);
        sq  += __shfl_down(sq, o, 64);
    }
    __shared__ float red[8];
    const int wid = threadIdx.x >> 6;
    if ((threadIdx.x & 63) == 0) { red[wid] = sum; red[4 + wid] = sq; }
    __syncthreads();
    sum = red[0] + red[1] + red[2] + red[3];
    sq  = red[4] + red[5] + red[6] + red[7];
    const float mean = sum * (1.0f / D_);
    const float var  = sq * (1.0f / D_) - mean * mean;
    const float rstd = rsqrtf(var + 1e-5f);
    u16* yr = y + base;
#pragma unroll
    for (int i = 0; i < 4; i++) {
        const int c = threadIdx.x + i * 256;
        yr[c] = f2b((v[i] - mean) * rstd * w[c] + b[c]);
    }
}

// ---------------- x3 = x2 + q0 + q1 + b2 (vectorized) ----------------
__global__ __launch_bounds__(256) void add3_bias_kernel(const float* __restrict__ x2,
                                                        const float* __restrict__ q0,
                                                        const float* __restrict__ q1,
                                                        const float* __restrict__ b2,
                                                        float* __restrict__ x3)
{
    const int i = blockIdx.x * 256 + threadIdx.x;   // float4 index over ROWS*1024/4
    float4 a  = ((const float4*)x2)[i];
    float4 c0 = ((const float4*)q0)[i];
    float4 c1 = ((const float4*)q1)[i];
    float4 bb = ((const float4*)b2)[i & 255];
    float4 r;
    r.x = a.x + c0.x + c1.x + bb.x;
    r.y = a.y + c0.y + c1.y + bb.y;
    r.z = a.z + c0.z + c1.z + bb.z;
    r.w = a.w + c0.w + c1.w + bb.w;
    ((float4*)x3)[i] = r;
}

// ======== 128x128-tile bf16 MFMA GEMM, BK=64, 4 waves, XOR-swizzled LDS ========
// R9-proven: m97 2-barrier skeleton, BK=64 (half the barrier drains, 32 KB LDS
// keeps ~4 blocks/CU), both-sides swizzle (source granule sg^(srow&7), read
// granule (ks*4+lhi)^(lane15&7)) -> 2-way max bank aliasing (free, m136).
// ACT: 0 none, 1 silu, 2 softplus. OUT: 1 bf16, 2 f32 atomicAdd, 3 f32 partial.
template <int ACT, bool BIAS, int OUT>
__global__ __launch_bounds__(256) void gemm128_bk64(
    const u16* __restrict__ A, const u16* __restrict__ W,
    const float* __restrict__ bias, void* __restrict__ Cout,
    int M, int K, int Nout, int kLen)
{
    __shared__ __align__(16) u16 As[128 * 64];   // 16 KB
    __shared__ __align__(16) u16 Bs[128 * 64];   // 16 KB
    const int tid = threadIdx.x;
    const int l = tid & 63, w = tid >> 6;
    const int bm = blockIdx.y * 128, bn = blockIdx.x * 128;
    const int kOff = blockIdx.z * kLen;

    const int srow = tid >> 3;                   // 0..31
    const int sg   = tid & 7;                    // LDS granule slot (linear)
    const int sgx  = sg ^ (srow & 7);            // swizzled SOURCE granule
    const u16* gA = A + (size_t)(bm + srow) * K + kOff + sgx * 8;
    const u16* gB = W + (size_t)(bn + srow) * K + kOff + sgx * 8;
    const int soff = srow * 64 + sg * 8;         // == tid*8 (lane-linear)

    const int lane15 = l & 15, lhi = l >> 4;
    const int key = lane15 & 7;
    const int wr = w >> 1, wc = w & 1;
    const u16* fArow = As + (wr * 64 + lane15) * 64;
    const u16* fBrow = Bs + (wc * 64 + lane15) * 64;

    f32x4 acc[4][4] = {};

    for (int kk = 0; kk < kLen; kk += 64) {
#pragma unroll
        for (int c = 0; c < 4; c++) {
            GLD16(gA + (size_t)c * 32 * K, As + c * 2048 + soff);
            GLD16(gB + (size_t)c * 32 * K, Bs + c * 2048 + soff);
        }
        gA += 64; gB += 64;
        __syncthreads();
#pragma unroll
        for (int ks = 0; ks < 2; ks++) {
            const int gsel = ((ks * 4 + lhi) ^ key) * 8;
            s16x8 af[4], bfr[4];
#pragma unroll
            for (int mi = 0; mi < 4; mi++) af[mi]  = *(const s16x8*)(fArow + mi * 16 * 64 + gsel);
#pragma unroll
            for (int ni = 0; ni < 4; ni++) bfr[ni] = *(const s16x8*)(fBrow + ni * 16 * 64 + gsel);
#pragma unroll
            for (int mi = 0; mi < 4; mi++)
#pragma unroll
                for (int ni = 0; ni < 4; ni++)
                    acc[mi][ni] = __builtin_amdgcn_mfma_f32_16x16x32_bf16(
                        af[mi], bfr[ni], acc[mi][ni], 0, 0, 0);
        }
        __syncthreads();
    }

#pragma unroll
    for (int ni = 0; ni < 4; ni++) {
        const int col = bn + wc * 64 + ni * 16 + lane15;
        if (col >= Nout) continue;
        const float bv = BIAS ? bias[col] : 0.0f;
#pragma unroll
        for (int mi = 0; mi < 4; mi++) {
#pragma unroll
            for (int r = 0; r < 4; r++) {
                const int row = bm + wr * 64 + mi * 16 + lhi * 4 + r;
                float v = acc[mi][ni][r] + bv;
                if (ACT == 1) v = silu_f(v);
                if (ACT == 2) v = (v > 20.0f) ? v : log1pf(__expf(v));
                if (OUT == 1) ((u16*)Cout)[(size_t)row * Nout + col] = f2b(v);
                if (OUT == 2) atomicAdd(&((float*)Cout)[(size_t)row * Nout + col], v);
                if (OUT == 3) ((float*)Cout)[((size_t)blockIdx.z * M + row) * Nout + col] = v;
            }
        }
    }
}

// ---------- classifier layer 1: split-K MFMA, reg-prefetch pipeline + swizzle ----------
#define KCH 512
__global__ __launch_bounds__(256) void gemm_cls_mfma(
    const float* __restrict__ A, const float* __restrict__ W,
    float* __restrict__ C)
{
    __shared__ __align__(16) u16 As[128 * 32];
    __shared__ __align__(16) u16 Bs[128 * 32];
    const int tid = threadIdx.x;
    const int l = tid & 63, w = tid >> 6;
    const int bn = blockIdx.x * 128;
    const int k0 = blockIdx.y * KCH;

    const int sr  = l >> 2;                 // 0..15
    const int sgl = l & 3;                  // source granule
    const int row = w * 16 + sr;            // 0..63
    const int skw = ((sgl ^ (sr & 3))) * 8; // swizzled write slot (key = row&3)
    const float* gA0 = A + (size_t)row * KCLS + k0 + sgl * 8;
    const float* gA1 = gA0 + (size_t)64 * KCLS;
    const float* gB0 = W + (size_t)(bn + row) * KCLS + k0 + sgl * 8;
    const float* gB1 = gB0 + (size_t)64 * KCLS;
    u16* lA0 = As + row * 32 + skw;  u16* lA1 = lA0 + 64 * 32;
    u16* lB0 = Bs + row * 32 + skw;  u16* lB1 = lB0 + 64 * 32;

    const int lane15 = l & 15, lhi = l >> 4;
    const int wr = w >> 1, wc = w & 1;
    const int rsel = (lhi ^ (lane15 & 3)) * 8;            // swizzled read slot
    const u16* fA = As + (wr * 64 + lane15) * 32 + rsel;
    const u16* fB = Bs + (wc * 64 + lane15) * 32 + rsel;

    f32x4 acc[4][4] = {};

    float4 a00 = *(const float4*)(gA0);  float4 a01 = *(const float4*)(gA0 + 4);
    float4 a10 = *(const float4*)(gA1);  float4 a11 = *(const float4*)(gA1 + 4);
    float4 b00 = *(const float4*)(gB0);  float4 b01 = *(const float4*)(gB0 + 4);
    float4 b10 = *(const float4*)(gB1);  float4 b11 = *(const float4*)(gB1 + 4);

    for (int ks = 0; ks < KCH / 32; ks++) {
        if (ks) {
            asm volatile("" ::: "memory");
            __builtin_amdgcn_s_barrier();           // prev iter's LDS reads done
            asm volatile("" ::: "memory");
        }
        uint4 r;
        r.x = pack2(a00.x, a00.y); r.y = pack2(a00.z, a00.w);
        r.z = pack2(a01.x, a01.y); r.w = pack2(a01.z, a01.w);
        *(uint4*)lA0 = r;
        r.x = pack2(a10.x, a10.y); r.y = pack2(a10.z, a10.w);
        r.z = pack2(a11.x, a11.y); r.w = pack2(a11.z, a11.w);
        *(uint4*)lA1 = r;
        r.x = pack2(b00.x, b00.y); r.y = pack2(b00.z, b00.w);
        r.z = pack2(b01.x, b01.y); r.w = pack2(b01.z, b01.w);
        *(uint4*)lB0 = r;
        r.x = pack2(b10.x, b10.y); r.y = pack2(b10.z, b10.w);
        r.z = pack2(b11.x, b11.y); r.w = pack2(b11.z, b11.w);
        *(uint4*)lB1 = r;
        if (ks + 1 < KCH / 32) {                    // prefetch next (overlaps barrier+MFMA)
            gA0 += 32; gA1 += 32; gB0 += 32; gB1 += 32;
            a00 = *(const float4*)(gA0);  a01 = *(const float4*)(gA0 + 4);
            a10 = *(const float4*)(gA1);  a11 = *(const float4*)(gA1 + 4);
            b00 = *(const float4*)(gB0);  b01 = *(const float4*)(gB0 + 4);
            b10 = *(const float4*)(gB1);  b11 = *(const float4*)(gB1 + 4);
        }
        asm volatile("s_waitcnt lgkmcnt(0)" ::: "memory");  // ds_writes visible (loads in flight)
        __builtin_amdgcn_s_barrier();
        asm volatile("" ::: "memory");
        s16x8 af[4], bfr[4];
#pragma unroll
        for (int mi = 0; mi < 4; mi++) af[mi]  = *(const s16x8*)(fA + mi * 16 * 32);
#pragma unroll
        for (int ni = 0; ni < 4; ni++) bfr[ni] = *(const s16x8*)(fB + ni * 16 * 32);
#pragma unroll
        for (int mi = 0; mi < 4; mi++)
#pragma unroll
            for (int ni = 0; ni < 4; ni++)
                acc[mi][ni] = __builtin_amdgcn_mfma_f32_16x16x32_bf16(
                    af[mi], bfr[ni], acc[mi][ni], 0, 0, 0);
    }

#pragma unroll
    for (int ni = 0; ni < 4; ni++) {
        const int col = bn + wc * 64 + ni * 16 + lane15;
#pragma unroll
        for (int mi = 0; mi < 4; mi++) {
#pragma unroll
            for (int r = 0; r < 4; r++) {
                const int m = wr * 64 + mi * 16 + lhi * 4 + r;
                atomicAdd(&C[(size_t)m * 1024 + col], acc[mi][ni][r]);
            }
        }
    }
}

// ------- causal conv1d (DC=5) + SiLU: rolling-window, one block per (b, half) -------
// Thread owns 8 fixed channels, iterates l=0..30 with a 5-deep uint4 register
// window: every input element loaded exactly ONCE (uint4, coalesced); weights
// loaded once per thread into registers (amortized over 31 rows). No LDS,
// no barrier; all window indices compile-time (rule #20 safe).
__global__ __launch_bounds__(128) void conv_silu_kernel(const u16* __restrict__ xz,
                                                        const float* __restrict__ cw,
                                                        const float* __restrict__ cb,
                                                        u16* __restrict__ uc)
{
    const int b  = blockIdx.y;
    const int d0 = (blockIdx.x * 128 + threadIdx.x) * 8;   // 0..2040
    const u16* up = xz + (size_t)b * L_ * (2 * DI_) + d0;
    u16* op = uc + (size_t)b * L_ * DI_ + d0;

    float wreg[8][DC_];
    float bias[8];
#pragma unroll
    for (int j = 0; j < 8; j++) {
        bias[j] = cb[d0 + j];
#pragma unroll
        for (int k = 0; k < DC_; k++) wreg[j][k] = cw[(d0 + j) * DC_ + k];
    }

    uint4 win[DC_];
#pragma unroll
    for (int k = 0; k < DC_; k++) win[k] = make_uint4(0, 0, 0, 0);

    for (int l = 0; l < L_; l++) {
#pragma unroll
        for (int k = 0; k < DC_ - 1; k++) win[k] = win[k + 1];
        win[DC_ - 1] = *(const uint4*)(up + (size_t)l * (2 * DI_));
        float acc[8];
#pragma unroll
        for (int j = 0; j < 8; j++) acc[j] = bias[j];
#pragma unroll
        for (int k = 0; k < DC_; k++) {
            const uint32_t uw[4] = {win[k].x, win[k].y, win[k].z, win[k].w};
#pragma unroll
            for (int j = 0; j < 8; j++)
                acc[j] = fmaf(b2f((u16)(uw[j >> 1] >> ((j & 1) * 16))), wreg[j][k], acc[j]);
        }
        uint4 r;
        r.x = pack2(silu_f(acc[0]), silu_f(acc[1]));
        r.y = pack2(silu_f(acc[2]), silu_f(acc[3]));
        r.z = pack2(silu_f(acc[4]), silu_f(acc[5]));
        r.w = pack2(silu_f(acc[6]), silu_f(acc[7]));
        *(uint4*)(op + (size_t)l * DI_) = r;
    }
}

// ---------------- extract xdbl[:, 0:64] -> bf16 (dt_proj A operand) ----------------
__global__ __launch_bounds__(256) void dtext_kernel(const float* __restrict__ xdbl,
                                                    u16* __restrict__ dtb)
{
    const int idx = blockIdx.x * 256 + threadIdx.x;   // over ROWS*16
    const int row = idx >> 4, c4 = (idx & 15) * 4;
    float4 v = *(const float4*)(xdbl + (size_t)row * 96 + c4);
    uint2 r;
    r.x = pack2(v.x, v.y); r.y = pack2(v.z, v.w);
    *(uint2*)(dtb + (size_t)row * 64 + c4) = r;
}

// ---------------- selective scan: one thread per (b, d), DS=16 states in regs ----------------
__global__ __launch_bounds__(256) void scan_kernel(const u16* __restrict__ dt,
                                                   const u16* __restrict__ uc,
                                                   const u16* __restrict__ xz,
                                                   const float* __restrict__ xdbl,
                                                   const float* __restrict__ A_log,
                                                   const float* __restrict__ D_ssm,
                                                   u16* __restrict__ y)
{
    const int idx = blockIdx.x * 256 + threadIdx.x;   // over B*DI
    const int d = idx & (DI_ - 1);
    const int b = idx >> 11;
    float A[DS_];
#pragma unroll
    for (int s = 0; s < DS_; s++) A[s] = -__expf(A_log[d * DS_ + s]);
    const float Dv = D_ssm[d];
    float h[DS_] = {};
    for (int l = 0; l < L_; l++) {
        const size_t bl = (size_t)b * L_ + l;
        const float dtv = b2f(dt[bl * DI_ + d]);
        const float uv  = b2f(uc[bl * DI_ + d]);
        const float zv  = b2f(xz[bl * (2 * DI_) + DI_ + d]);
        const float* Bp = xdbl + bl * (DTR_ + 2 * DS_) + DTR_;
        const float* Cp = Bp + DS_;
        float yv = 0.f;
#pragma unroll
        for (int s = 0; s < DS_; s++) {
            h[s] = fmaf(h[s], __expf(dtv * A[s]), dtv * Bp[s] * uv);
            yv = fmaf(h[s], Cp[s], yv);
        }
        yv = fmaf(uv, Dv, yv);
        yv *= silu_f(zv);
        y[bl * DI_ + d] = f2b(yv);
    }
}

// ---------------- classifier layer 2 ----------------
__global__ __launch_bounds__(256) void cls2_kernel(const float* __restrict__ c,
                                                   const float* __restrict__ b1,
                                                   const float* __restrict__ W2,
                                                   const float* __restrict__ b2,
                                                   float* __restrict__ out)
{
    const int b = blockIdx.x;
    float s = 0.f;
    for (int n = threadIdx.x; n < D_; n += 256) {
        float v = c[b * D_ + n] + b1[n];
        v = silu_f(v);
        s = fmaf(v, W2[n], s);
    }
#pragma unroll
    for (int o = 32; o > 0; o >>= 1) s += __shfl_down(s, o, 64);
    __shared__ float red[4];
    const int wid = threadIdx.x >> 6;
    if ((threadIdx.x & 63) == 0) red[wid] = s;
    __syncthreads();
    if (threadIdx.x == 0) out[b] = red[0] + red[1] + red[2] + red[3] + b2[0];
}

extern "C" void kernel_launch(void* const* d_in, const int* in_sizes, int n_in,
                              void* d_out, int out_size, void* d_ws, size_t ws_size,
                              hipStream_t stream)
{
    const float* x         = (const float*)d_in[0];
    const float* n1w       = (const float*)d_in[1];
    const float* n1b       = (const float*)d_in[2];
    const float* in_projW  = (const float*)d_in[3];
    const float* conv_w    = (const float*)d_in[4];
    const float* conv_b    = (const float*)d_in[5];
    const float* x_projW   = (const float*)d_in[6];
    const float* dt_projW  = (const float*)d_in[7];
    const float* dt_projb  = (const float*)d_in[8];
    const float* A_log     = (const float*)d_in[9];
    const float* D_ssm     = (const float*)d_in[10];
    const float* out_projW = (const float*)d_in[11];
    const float* n2w       = (const float*)d_in[12];
    const float* n2b       = (const float*)d_in[13];
    const float* ffn_W1    = (const float*)d_in[14];
    const float* ffn_b1    = (const float*)d_in[15];
    const float* ffn_W2    = (const float*)d_in[16];
    const float* ffn_b2    = (const float*)d_in[17];
    const float* cls_W1    = (const float*)d_in[18];
    const float* cls_b1    = (const float*)d_in[19];
    const float* cls_W2    = (const float*)d_in[20];
    const float* cls_b2    = (const float*)d_in[21];

    // ---- workspace layout ----
    u16* base   = (u16*)d_ws;
    u16* xz_b   = base;                               // ROWS*4096
    u16* uc_b   = xz_b + (size_t)ROWS * 4096;         // ROWS*2048
    u16* dt_b   = uc_b + (size_t)ROWS * 2048;         // ROWS*2048
    u16* y_b    = dt_b + (size_t)ROWS * 2048;         // ROWS*2048
    u16* h_b    = y_b + (size_t)ROWS * 2048;          // ROWS*1024
    float* x2   = (float*)(h_b + (size_t)ROWS * 1024);// ROWS*1024 f32
    float* xdbl = x2 + (size_t)ROWS * 1024;           // ROWS*96 f32
    u16* dtb    = (u16*)(xdbl + (size_t)ROWS * 96);   // ROWS*64
    u16* wbuf   = dtb + (size_t)ROWS * 64;            // WTOT
    float* clsh = (float*)(wbuf + (size_t)WTOT);      // 128*1024 f32
    float* pq   = clsh + (size_t)B_ * D_;             // 2 * ROWS*1024 f32 (split-K partials)

    float* outv = (float*)d_out;    // (B,1)
    float* x3   = outv + B_;        // (B,L,D)

    // 0. all weight conversions
    f2b_all_kernel<<<dim3(5312), dim3(256), 0, stream>>>(
        in_projW, out_projW, ffn_W1, ffn_W2, x_projW, dt_projW, wbuf);
    // 1. LN1 -> bf16
    ln_kernel<<<dim3(ROWS), dim3(256), 0, stream>>>(x, n1w, n1b, h_b);
    // 2. in_proj (BK=64 swz) -> bf16 xz   (3968 x 4096, K=1024), 992 blocks
    gemm128_bk64<0, false, 1><<<dim3(32, 31, 1), dim3(256), 0, stream>>>(
        h_b, wbuf + W_IN, nullptr, xz_b, ROWS, D_, 2 * DI_, D_);
    // 3. causal conv + SiLU (rolling-window, 1-load-per-element) -> bf16
    conv_silu_kernel<<<dim3(2, B_), dim3(128), 0, stream>>>(xz_b, conv_w, conv_b, uc_b);
    // 4. x_proj (BK=64 swz, split-K x16, atomic f32): xdbl = uc @ x_proj_W^T  (3968 x 96)
    hipMemsetAsync(xdbl, 0, (size_t)ROWS * 96 * sizeof(float), stream);
    gemm128_bk64<0, false, 2><<<dim3(1, 31, 16), dim3(256), 0, stream>>>(
        uc_b, wbuf + W_XP, nullptr, xdbl, ROWS, DI_, DTR_ + 2 * DS_, 128);
    // 5. dt_proj (BK=64 swz, softplus) -> bf16   (3968 x 2048, K=64)
    dtext_kernel<<<dim3(ROWS * 16 / 256), dim3(256), 0, stream>>>(xdbl, dtb);
    gemm128_bk64<2, true, 1><<<dim3(16, 31, 1), dim3(256), 0, stream>>>(
        dtb, wbuf + W_DT, dt_projb, dt_b, ROWS, DTR_, DI_, DTR_);
    // 6. selective scan (+ skip + gate) -> bf16 y
    scan_kernel<<<dim3(B_ * DI_ / 256), dim3(256), 0, stream>>>(
        dt_b, uc_b, xz_b, xdbl, A_log, D_ssm, y_b);
    // 7. out_proj (BK=64 swz, split-K z=2) -> partials p0,p1   (3968 x 1024, K=2048)
    gemm128_bk64<0, false, 3><<<dim3(8, 31, 2), dim3(256), 0, stream>>>(
        y_b, wbuf + W_OUT, nullptr, pq, ROWS, DI_, D_, 1024);
    // 8. fused combine + LN2: x2 = x + p0 + p1, h2 = LN(x2) -> bf16
    ln2_fuse_kernel<<<dim3(ROWS), dim3(256), 0, stream>>>(
        x, pq, pq + (size_t)ROWS * D_, n2w, n2b, x2, h_b);
    // 9. ffn1 (BK=64 swz) + bias + SiLU -> bf16   (3968 x 2048, K=1024), 496 blocks
    gemm128_bk64<1, true, 1><<<dim3(16, 31, 1), dim3(256), 0, stream>>>(
        h_b, wbuf + W_F1, ffn_b1, uc_b, ROWS, D_, 2 * D_, D_);
    // 10. ffn2 (BK=64 swz, split-K z=2) -> partials q0,q1   (3968 x 1024, K=2048)
    gemm128_bk64<0, false, 3><<<dim3(8, 31, 2), dim3(256), 0, stream>>>(
        uc_b, wbuf + W_F2, nullptr, pq, ROWS, 2 * D_, D_, 1024);
    // 11. combine: x3 = x2 + q0 + q1 + b2 -> d_out
    add3_bias_kernel<<<dim3(ROWS * D_ / 4 / 256), dim3(256), 0, stream>>>(
        x2, pq, pq + (size_t)ROWS * D_, ffn_b2, x3);
    // 12. classifier layer 1: split-K MFMA, reg-prefetch pipeline + swizzle
    hipMemsetAsync(clsh, 0, (size_t)B_ * D_ * sizeof(float), stream);
    gemm_cls_mfma<<<dim3(1024 / 128, KCLS / KCH), dim3(256), 0, stream>>>(x3, cls_W1, clsh);
    // 13. classifier layer 2
    cls2_kernel<<<dim3(B_), dim3(256), 0, stream>>>(clsh, cls_b1, cls_W2, cls_b2, outv);
}

// Round 13
// 383.718 us; speedup vs baseline: 1.1390x; 1.0070x over previous
//
#include <hip/hip_runtime.h>
#include <cstddef>
#include <cstdint>

#define B_   128
#define L_   31
#define D_   1024
#define DI_  2048
#define DS_  16
#define DC_  5
#define DTR_ 64
#define ROWS (B_ * L_)   // 3968
#define KCLS (L_ * D_)   // 31744

// weight-buffer offsets (u16 elements)
#define W_IN  0          // 4096x1024
#define W_OUT 4194304    // 1024x2048
#define W_F1  6291456    // 2048x1024
#define W_F2  8388608    // 1024x2048
#define W_XP  10485760   // 128x2048 (rows 96..127 zero)
#define W_DT  10747904   // 2048x64
#define WTOT  10878976

typedef unsigned short u16;
typedef __attribute__((ext_vector_type(8))) short s16x8;
typedef __attribute__((ext_vector_type(4))) float f32x4;

__device__ __forceinline__ float silu_f(float x) { return x / (1.0f + __expf(-x)); }

__device__ __forceinline__ u16 f2b(float f) {
    union { float f; uint32_t u; } c; c.f = f;
    uint32_t u = c.u + 0x7FFF + ((c.u >> 16) & 1);
    return (u16)(u >> 16);
}
__device__ __forceinline__ float b2f(u16 b) {
    union { uint32_t u; float f; } c; c.u = ((uint32_t)b) << 16;
    return c.f;
}
__device__ __forceinline__ uint32_t pack2(float lo, float hi) {
    return (uint32_t)f2b(lo) | ((uint32_t)f2b(hi) << 16);
}
__device__ __forceinline__ void cvt8(const float* __restrict__ s, u16* __restrict__ d) {
    const float4* p = (const float4*)s;
    float4 a = p[0], b = p[1];
    uint4 r;
    r.x = pack2(a.x, a.y); r.y = pack2(a.z, a.w);
    r.z = pack2(b.x, b.y); r.w = pack2(b.z, b.w);
    *(uint4*)d = r;
}

#define GLD16(g, s) __builtin_amdgcn_global_load_lds( \
    (const __attribute__((address_space(1))) void*)(g), \
    (__attribute__((address_space(3))) void*)(s), 16, 0, 0)

// ---------------- all-weights fp32 -> bf16 (single launch) ----------------
__global__ __launch_bounds__(256) void f2b_all_kernel(
    const float* __restrict__ inW, const float* __restrict__ outW,
    const float* __restrict__ f1W, const float* __restrict__ f2W,
    const float* __restrict__ xpW, const float* __restrict__ dtW,
    u16* __restrict__ wbuf)
{
    int g = blockIdx.x * 256 + threadIdx.x;
    if (g < 524288) { cvt8(inW + (size_t)g * 8, wbuf + W_IN + (size_t)g * 8); return; }
    g -= 524288;
    if (g < 262144) { cvt8(outW + (size_t)g * 8, wbuf + W_OUT + (size_t)g * 8); return; }
    g -= 262144;
    if (g < 262144) { cvt8(f1W + (size_t)g * 8, wbuf + W_F1 + (size_t)g * 8); return; }
    g -= 262144;
    if (g < 262144) { cvt8(f2W + (size_t)g * 8, wbuf + W_F2 + (size_t)g * 8); return; }
    g -= 262144;
    if (g < 32768) {   // x_proj, padded 96 -> 128 rows
        const int row = g >> 8, col8 = (g & 255) * 8;
        u16* d = wbuf + W_XP + (size_t)row * 2048 + col8;
        if (row < 96) cvt8(xpW + (size_t)row * 2048 + col8, d);
        else *(uint4*)d = make_uint4(0, 0, 0, 0);
        return;
    }
    g -= 32768;
    if (g < 16384) cvt8(dtW + (size_t)g * 8, wbuf + W_DT + (size_t)g * 8);
}

// ---------------- LayerNorm (one block per row, D=1024) -> bf16 out ----------------
__global__ __launch_bounds__(256) void ln_kernel(const float* __restrict__ x,
                                                 const float* __restrict__ w,
                                                 const float* __restrict__ b,
                                                 u16* __restrict__ y)
{
    const int row = blockIdx.x;
    const float* xr = x + (size_t)row * D_;
    float v[4];
    float sum = 0.f, sq = 0.f;
#pragma unroll
    for (int i = 0; i < 4; i++) {
        v[i] = xr[threadIdx.x + i * 256];
        sum += v[i];
        sq  += v[i] * v[i];
    }
#pragma unroll
    for (int o = 32; o > 0; o >>= 1) {
        sum += __shfl_down(sum, o, 64);
        sq  += __shfl_down(sq, o, 64);
    }
    __shared__ float red[8];
    const int wid = threadIdx.x >> 6;
    if ((threadIdx.x & 63) == 0) { red[wid] = sum; red[4 + wid] = sq; }
    __syncthreads();
    sum = red[0] + red[1] + red[2] + red[3];
    sq  = red[4] + red[5] + red[6] + red[7];
    const float mean = sum * (1.0f / D_);
    const float var  = sq * (1.0f / D_) - mean * mean;
    const float rstd = rsqrtf(var + 1e-5f);
    u16* yr = y + (size_t)row * D_;
#pragma unroll
    for (int i = 0; i < 4; i++) {
        const int c = threadIdx.x + i * 256;
        yr[c] = f2b((v[i] - mean) * rstd * w[c] + b[c]);
    }
}

// ------- fused: x2 = x + p0 + p1 (bf16 partials); h2 = LN(x2) -> bf16 (vectorized) -------
__global__ __launch_bounds__(256) void ln2_fuse_kernel(const float* __restrict__ x,
                                                       const u16* __restrict__ p0,
                                                       const u16* __restrict__ p1,
                                                       const float* __restrict__ w,
                                                       const float* __restrict__ b,
                                                       float* __restrict__ x2,
                                                       u16* __restrict__ y)
{
    const int row = blockIdx.x;
    const size_t base = (size_t)row * D_;
    const int c4 = threadIdx.x * 4;
    float4 xv = *(const float4*)(x + base + c4);
    uint2 p0v = *(const uint2*)(p0 + base + c4);
    uint2 p1v = *(const uint2*)(p1 + base + c4);
    float v[4];
    v[0] = xv.x + b2f((u16)p0v.x)         + b2f((u16)p1v.x);
    v[1] = xv.y + b2f((u16)(p0v.x >> 16)) + b2f((u16)(p1v.x >> 16));
    v[2] = xv.z + b2f((u16)p0v.y)         + b2f((u16)(p1v.y));
    v[3] = xv.w + b2f((u16)(p0v.y >> 16)) + b2f((u16)(p1v.y >> 16));
    *(float4*)(x2 + base + c4) = make_float4(v[0], v[1], v[2], v[3]);
    float sum = v[0] + v[1] + v[2] + v[3];
    float sq  = v[0]*v[0] + v[1]*v[1] + v[2]*v[2] + v[3]*v[3];
#pragma unroll
    for (int o = 32; o > 0; o >>= 1) {
        sum += __shfl_down(sum, o, 64);
        sq  += __shfl_down(sq, o, 64);
    }
    __shared__ float red[8];
    const int wid = threadIdx.x >> 6;
    if ((threadIdx.x & 63) == 0) { red[wid] = sum; red[4 + wid] = sq; }
    __syncthreads();
    sum = red[0] + red[1] + red[2] + red[3];
    sq  = red[4] + red[5] + red[6] + red[7];
    const float mean = sum * (1.0f / D_);
    const float var  = sq * (1.0f / D_) - mean * mean;
    const float rstd = rsqrtf(var + 1e-5f);
    float4 wv = *(const float4*)(w + c4);
    float4 bv = *(const float4*)(b + c4);
    uint2 r;
    r.x = pack2((v[0] - mean) * rstd * wv.x + bv.x, (v[1] - mean) * rstd * wv.y + bv.y);
    r.y = pack2((v[2] - mean) * rstd * wv.z + bv.z, (v[3] - mean) * rstd * wv.w + bv.w);
    *(uint2*)(y + base + c4) = r;
}

// ---------------- x3 = x2 + q0 + q1 + b2 (bf16 partials, vectorized) ----------------
__global__ __launch_bounds__(256) void add3_bias_kernel(const float* __restrict__ x2,
                                                        const u16* __restrict__ q0,
                                                        const u16* __restrict__ q1,
                                                        const float* __restrict__ b2,
                                                        float* __restrict__ x3)
{
    const int i = blockIdx.x * 256 + threadIdx.x;   // float4 index over ROWS*1024/4
    float4 a  = ((const float4*)x2)[i];
    uint2 c0 = ((const uint2*)q0)[i];
    uint2 c1 = ((const uint2*)q1)[i];
    float4 bb = ((const float4*)b2)[i & 255];
    float4 r;
    r.x = a.x + b2f((u16)c0.x)         + b2f((u16)c1.x)         + bb.x;
    r.y = a.y + b2f((u16)(c0.x >> 16)) + b2f((u16)(c1.x >> 16)) + bb.y;
    r.z = a.z + b2f((u16)c0.y)         + b2f((u16)c1.y)         + bb.z;
    r.w = a.w + b2f((u16)(c0.y >> 16)) + b2f((u16)(c1.y >> 16)) + bb.w;
    ((float4*)x3)[i] = r;
}

// ======== 128x128-tile bf16 MFMA GEMM, BK=64, 4 waves, XOR-swizzled LDS ========
// R9-proven: m97 2-barrier skeleton, BK=64 (half the barrier drains, 32 KB LDS
// keeps ~4 blocks/CU), both-sides swizzle (source granule sg^(srow&7), read
// granule (ks*4+lhi)^(lane15&7)) -> 2-way max bank aliasing (free, m136).
// ACT: 0 none, 1 silu, 2 softplus.
// OUT: 1 bf16, 2 f32 atomicAdd, 3 f32 partial (z-idx), 4 bf16 partial (z-idx).
template <int ACT, bool BIAS, int OUT>
__global__ __launch_bounds__(256) void gemm128_bk64(
    const u16* __restrict__ A, const u16* __restrict__ W,
    const float* __restrict__ bias, void* __restrict__ Cout,
    int M, int K, int Nout, int kLen)
{
    __shared__ __align__(16) u16 As[128 * 64];   // 16 KB
    __shared__ __align__(16) u16 Bs[128 * 64];   // 16 KB
    const int tid = threadIdx.x;
    const int l = tid & 63, w = tid >> 6;
    const int bm = blockIdx.y * 128, bn = blockIdx.x * 128;
    const int kOff = blockIdx.z * kLen;

    const int srow = tid >> 3;                   // 0..31
    const int sg   = tid & 7;                    // LDS granule slot (linear)
    const int sgx  = sg ^ (srow & 7);            // swizzled SOURCE granule
    const u16* gA = A + (size_t)(bm + srow) * K + kOff + sgx * 8;
    const u16* gB = W + (size_t)(bn + srow) * K + kOff + sgx * 8;
    const int soff = srow * 64 + sg * 8;         // == tid*8 (lane-linear)

    const int lane15 = l & 15, lhi = l >> 4;
    const int key = lane15 & 7;
    const int wr = w >> 1, wc = w & 1;
    const u16* fArow = As + (wr * 64 + lane15) * 64;
    const u16* fBrow = Bs + (wc * 64 + lane15) * 64;

    f32x4 acc[4][4] = {};

    for (int kk = 0; kk < kLen; kk += 64) {
#pragma unroll
        for (int c = 0; c < 4; c++) {
            GLD16(gA + (size_t)c * 32 * K, As + c * 2048 + soff);
            GLD16(gB + (size_t)c * 32 * K, Bs + c * 2048 + soff);
        }
        gA += 64; gB += 64;
        __syncthreads();
#pragma unroll
        for (int ks = 0; ks < 2; ks++) {
            const int gsel = ((ks * 4 + lhi) ^ key) * 8;
            s16x8 af[4], bfr[4];
#pragma unroll
            for (int mi = 0; mi < 4; mi++) af[mi]  = *(const s16x8*)(fArow + mi * 16 * 64 + gsel);
#pragma unroll
            for (int ni = 0; ni < 4; ni++) bfr[ni] = *(const s16x8*)(fBrow + ni * 16 * 64 + gsel);
#pragma unroll
            for (int mi = 0; mi < 4; mi++)
#pragma unroll
                for (int ni = 0; ni < 4; ni++)
                    acc[mi][ni] = __builtin_amdgcn_mfma_f32_16x16x32_bf16(
                        af[mi], bfr[ni], acc[mi][ni], 0, 0, 0);
        }
        __syncthreads();
    }

#pragma unroll
    for (int ni = 0; ni < 4; ni++) {
        const int col = bn + wc * 64 + ni * 16 + lane15;
        if (col >= Nout) continue;
        const float bv = BIAS ? bias[col] : 0.0f;
#pragma unroll
        for (int mi = 0; mi < 4; mi++) {
#pragma unroll
            for (int r = 0; r < 4; r++) {
                const int row = bm + wr * 64 + mi * 16 + lhi * 4 + r;
                float v = acc[mi][ni][r] + bv;
                if (ACT == 1) v = silu_f(v);
                if (ACT == 2) v = (v > 20.0f) ? v : log1pf(__expf(v));
                if (OUT == 1) ((u16*)Cout)[(size_t)row * Nout + col] = f2b(v);
                if (OUT == 2) atomicAdd(&((float*)Cout)[(size_t)row * Nout + col], v);
                if (OUT == 3) ((float*)Cout)[((size_t)blockIdx.z * M + row) * Nout + col] = v;
                if (OUT == 4) ((u16*)Cout)[((size_t)blockIdx.z * M + row) * Nout + col] = f2b(v);
            }
        }
    }
}

// ---------- classifier layer 1: split-K MFMA, reg-prefetch pipeline + swizzle ----------
#define KCH 512
__global__ __launch_bounds__(256) void gemm_cls_mfma(
    const float* __restrict__ A, const float* __restrict__ W,
    float* __restrict__ C)
{
    __shared__ __align__(16) u16 As[128 * 32];
    __shared__ __align__(16) u16 Bs[128 * 32];
    const int tid = threadIdx.x;
    const int l = tid & 63, w = tid >> 6;
    const int bn = blockIdx.x * 128;
    const int k0 = blockIdx.y * KCH;

    const int sr  = l >> 2;                 // 0..15
    const int sgl = l & 3;                  // source granule
    const int row = w * 16 + sr;            // 0..63
    const int skw = ((sgl ^ (sr & 3))) * 8; // swizzled write slot (key = row&3)
    const float* gA0 = A + (size_t)row * KCLS + k0 + sgl * 8;
    const float* gA1 = gA0 + (size_t)64 * KCLS;
    const float* gB0 = W + (size_t)(bn + row) * KCLS + k0 + sgl * 8;
    const float* gB1 = gB0 + (size_t)64 * KCLS;
    u16* lA0 = As + row * 32 + skw;  u16* lA1 = lA0 + 64 * 32;
    u16* lB0 = Bs + row * 32 + skw;  u16* lB1 = lB0 + 64 * 32;

    const int lane15 = l & 15, lhi = l >> 4;
    const int wr = w >> 1, wc = w & 1;
    const int rsel = (lhi ^ (lane15 & 3)) * 8;            // swizzled read slot
    const u16* fA = As + (wr * 64 + lane15) * 32 + rsel;
    const u16* fB = Bs + (wc * 64 + lane15) * 32 + rsel;

    f32x4 acc[4][4] = {};

    float4 a00 = *(const float4*)(gA0);  float4 a01 = *(const float4*)(gA0 + 4);
    float4 a10 = *(const float4*)(gA1);  float4 a11 = *(const float4*)(gA1 + 4);
    float4 b00 = *(const float4*)(gB0);  float4 b01 = *(const float4*)(gB0 + 4);
    float4 b10 = *(const float4*)(gB1);  float4 b11 = *(const float4*)(gB1 + 4);

    for (int ks = 0; ks < KCH / 32; ks++) {
        if (ks) {
            asm volatile("" ::: "memory");
            __builtin_amdgcn_s_barrier();           // prev iter's LDS reads done
            asm volatile("" ::: "memory");
        }
        uint4 r;
        r.x = pack2(a00.x, a00.y); r.y = pack2(a00.z, a00.w);
        r.z = pack2(a01.x, a01.y); r.w = pack2(a01.z, a01.w);
        *(uint4*)lA0 = r;
        r.x = pack2(a10.x, a10.y); r.y = pack2(a10.z, a10.w);
        r.z = pack2(a11.x, a11.y); r.w = pack2(a11.z, a11.w);
        *(uint4*)lA1 = r;
        r.x = pack2(b00.x, b00.y); r.y = pack2(b00.z, b00.w);
        r.z = pack2(b01.x, b01.y); r.w = pack2(b01.z, b01.w);
        *(uint4*)lB0 = r;
        r.x = pack2(b10.x, b10.y); r.y = pack2(b10.z, b10.w);
        r.z = pack2(b11.x, b11.y); r.w = pack2(b11.z, b11.w);
        *(uint4*)lB1 = r;
        if (ks + 1 < KCH / 32) {                    // prefetch next (overlaps barrier+MFMA)
            gA0 += 32; gA1 += 32; gB0 += 32; gB1 += 32;
            a00 = *(const float4*)(gA0);  a01 = *(const float4*)(gA0 + 4);
            a10 = *(const float4*)(gA1);  a11 = *(const float4*)(gA1 + 4);
            b00 = *(const float4*)(gB0);  b01 = *(const float4*)(gB0 + 4);
            b10 = *(const float4*)(gB1);  b11 = *(const float4*)(gB1 + 4);
        }
        asm volatile("s_waitcnt lgkmcnt(0)" ::: "memory");  // ds_writes visible (loads in flight)
        __builtin_amdgcn_s_barrier();
        asm volatile("" ::: "memory");
        s16x8 af[4], bfr[4];
#pragma unroll
        for (int mi = 0; mi < 4; mi++) af[mi]  = *(const s16x8*)(fA + mi * 16 * 32);
#pragma unroll
        for (int ni = 0; ni < 4; ni++) bfr[ni] = *(const s16x8*)(fB + ni * 16 * 32);
#pragma unroll
        for (int mi = 0; mi < 4; mi++)
#pragma unroll
            for (int ni = 0; ni < 4; ni++)
                acc[mi][ni] = __builtin_amdgcn_mfma_f32_16x16x32_bf16(
                    af[mi], bfr[ni], acc[mi][ni], 0, 0, 0);
    }

#pragma unroll
    for (int ni = 0; ni < 4; ni++) {
        const int col = bn + wc * 64 + ni * 16 + lane15;
#pragma unroll
        for (int mi = 0; mi < 4; mi++) {
#pragma unroll
            for (int r = 0; r < 4; r++) {
                const int m = wr * 64 + mi * 16 + lhi * 4 + r;
                atomicAdd(&C[(size_t)m * 1024 + col], acc[mi][ni][r]);
            }
        }
    }
}

// ------- causal conv1d (DC=5) + SiLU: rolling-window, one block per (b, half) -------
__global__ __launch_bounds__(128) void conv_silu_kernel(const u16* __restrict__ xz,
                                                        const float* __restrict__ cw,
                                                        const float* __restrict__ cb,
                                                        u16* __restrict__ uc)
{
    const int b  = blockIdx.y;
    const int d0 = (blockIdx.x * 128 + threadIdx.x) * 8;   // 0..2040
    const u16* up = xz + (size_t)b * L_ * (2 * DI_) + d0;
    u16* op = uc + (size_t)b * L_ * DI_ + d0;

    float wreg[8][DC_];
    float bias[8];
#pragma unroll
    for (int j = 0; j < 8; j++) {
        bias[j] = cb[d0 + j];
#pragma unroll
        for (int k = 0; k < DC_; k++) wreg[j][k] = cw[(d0 + j) * DC_ + k];
    }

    uint4 win[DC_];
#pragma unroll
    for (int k = 0; k < DC_; k++) win[k] = make_uint4(0, 0, 0, 0);

    for (int l = 0; l < L_; l++) {
#pragma unroll
        for (int k = 0; k < DC_ - 1; k++) win[k] = win[k + 1];
        win[DC_ - 1] = *(const uint4*)(up + (size_t)l * (2 * DI_));
        float acc[8];
#pragma unroll
        for (int j = 0; j < 8; j++) acc[j] = bias[j];
#pragma unroll
        for (int k = 0; k < DC_; k++) {
            const uint32_t uw[4] = {win[k].x, win[k].y, win[k].z, win[k].w};
#pragma unroll
            for (int j = 0; j < 8; j++)
                acc[j] = fmaf(b2f((u16)(uw[j >> 1] >> ((j & 1) * 16))), wreg[j][k], acc[j]);
        }
        uint4 r;
        r.x = pack2(silu_f(acc[0]), silu_f(acc[1]));
        r.y = pack2(silu_f(acc[2]), silu_f(acc[3]));
        r.z = pack2(silu_f(acc[4]), silu_f(acc[5]));
        r.w = pack2(silu_f(acc[6]), silu_f(acc[7]));
        *(uint4*)(op + (size_t)l * DI_) = r;
    }
}

// ---------------- extract xdbl[:, 0:64] -> bf16 (dt_proj A operand) ----------------
__global__ __launch_bounds__(256) void dtext_kernel(const float* __restrict__ xdbl,
                                                    u16* __restrict__ dtb)
{
    const int idx = blockIdx.x * 256 + threadIdx.x;   // over ROWS*16
    const int row = idx >> 4, c4 = (idx & 15) * 4;
    float4 v = *(const float4*)(xdbl + (size_t)row * 96 + c4);
    uint2 r;
    r.x = pack2(v.x, v.y); r.y = pack2(v.z, v.w);
    *(uint2*)(dtb + (size_t)row * 64 + c4) = r;
}

// ---------------- selective scan: one thread per (b, d), DS=16 states in regs ----------------
__global__ __launch_bounds__(256) void scan_kernel(const u16* __restrict__ dt,
                                                   const u16* __restrict__ uc,
                                                   const u16* __restrict__ xz,
                                                   const float* __restrict__ xdbl,
                                                   const float* __restrict__ A_log,
                                                   const float* __restrict__ D_ssm,
                                                   u16* __restrict__ y)
{
    const int idx = blockIdx.x * 256 + threadIdx.x;   // over B*DI
    const int d = idx & (DI_ - 1);
    const int b = idx >> 11;
    float A[DS_];
#pragma unroll
    for (int s = 0; s < DS_; s++) A[s] = -__expf(A_log[d * DS_ + s]);
    const float Dv = D_ssm[d];
    float h[DS_] = {};
    for (int l = 0; l < L_; l++) {
        const size_t bl = (size_t)b * L_ + l;
        const float dtv = b2f(dt[bl * DI_ + d]);
        const float uv  = b2f(uc[bl * DI_ + d]);
        const float zv  = b2f(xz[bl * (2 * DI_) + DI_ + d]);
        const float* Bp = xdbl + bl * (DTR_ + 2 * DS_) + DTR_;
        const float* Cp = Bp + DS_;
        float yv = 0.f;
#pragma unroll
        for (int s = 0; s < DS_; s++) {
            h[s] = fmaf(h[s], __expf(dtv * A[s]), dtv * Bp[s] * uv);
            yv = fmaf(h[s], Cp[s], yv);
        }
        yv = fmaf(uv, Dv, yv);
        yv *= silu_f(zv);
        y[bl * DI_ + d] = f2b(yv);
    }
}

// ---------------- classifier layer 2 ----------------
__global__ __launch_bounds__(256) void cls2_kernel(const float* __restrict__ c,
                                                   const float* __restrict__ b1,
                                                   const float* __restrict__ W2,
                                                   const float* __restrict__ b2,
                                                   float* __restrict__ out)
{
    const int b = blockIdx.x;
    float s = 0.f;
    for (int n = threadIdx.x; n < D_; n += 256) {
        float v = c[b * D_ + n] + b1[n];
        v = silu_f(v);
        s = fmaf(v, W2[n], s);
    }
#pragma unroll
    for (int o = 32; o > 0; o >>= 1) s += __shfl_down(s, o, 64);
    __shared__ float red[4];
    const int wid = threadIdx.x >> 6;
    if ((threadIdx.x & 63) == 0) red[wid] = s;
    __syncthreads();
    if (threadIdx.x == 0) out[b] = red[0] + red[1] + red[2] + red[3] + b2[0];
}

extern "C" void kernel_launch(void* const* d_in, const int* in_sizes, int n_in,
                              void* d_out, int out_size, void* d_ws, size_t ws_size,
                              hipStream_t stream)
{
    const float* x         = (const float*)d_in[0];
    const float* n1w       = (const float*)d_in[1];
    const float* n1b       = (const float*)d_in[2];
    const float* in_projW  = (const float*)d_in[3];
    const float* conv_w    = (const float*)d_in[4];
    const float* conv_b    = (const float*)d_in[5];
    const float* x_projW   = (const float*)d_in[6];
    const float* dt_projW  = (const float*)d_in[7];
    const float* dt_projb  = (const float*)d_in[8];
    const float* A_log     = (const float*)d_in[9];
    const float* D_ssm     = (const float*)d_in[10];
    const float* out_projW = (const float*)d_in[11];
    const float* n2w       = (const float*)d_in[12];
    const float* n2b       = (const float*)d_in[13];
    const float* ffn_W1    = (const float*)d_in[14];
    const float* ffn_b1    = (const float*)d_in[15];
    const float* ffn_W2    = (const float*)d_in[16];
    const float* ffn_b2    = (const float*)d_in[17];
    const float* cls_W1    = (const float*)d_in[18];
    const float* cls_b1    = (const float*)d_in[19];
    const float* cls_W2    = (const float*)d_in[20];
    const float* cls_b2    = (const float*)d_in[21];

    // ---- workspace layout ----
    u16* base   = (u16*)d_ws;
    u16* xz_b   = base;                               // ROWS*4096
    u16* uc_b   = xz_b + (size_t)ROWS * 4096;         // ROWS*2048
    u16* dt_b   = uc_b + (size_t)ROWS * 2048;         // ROWS*2048
    u16* y_b    = dt_b + (size_t)ROWS * 2048;         // ROWS*2048
    u16* h_b    = y_b + (size_t)ROWS * 2048;          // ROWS*1024
    float* x2   = (float*)(h_b + (size_t)ROWS * 1024);// ROWS*1024 f32
    float* xdbl = x2 + (size_t)ROWS * 1024;           // ROWS*96 f32
    u16* dtb    = (u16*)(xdbl + (size_t)ROWS * 96);   // ROWS*64
    u16* wbuf   = dtb + (size_t)ROWS * 64;            // WTOT
    float* clsh = (float*)(wbuf + (size_t)WTOT);      // 128*1024 f32
    u16* pq     = (u16*)(clsh + (size_t)B_ * D_);     // 2 * ROWS*1024 u16 (bf16 split-K partials)

    float* outv = (float*)d_out;    // (B,1)
    float* x3   = outv + B_;        // (B,L,D)

    // 0. all weight conversions
    f2b_all_kernel<<<dim3(5312), dim3(256), 0, stream>>>(
        in_projW, out_projW, ffn_W1, ffn_W2, x_projW, dt_projW, wbuf);
    // 1. LN1 -> bf16
    ln_kernel<<<dim3(ROWS), dim3(256), 0, stream>>>(x, n1w, n1b, h_b);
    // 2. in_proj (BK=64 swz) -> bf16 xz   (3968 x 4096, K=1024), 992 blocks
    gemm128_bk64<0, false, 1><<<dim3(32, 31, 1), dim3(256), 0, stream>>>(
        h_b, wbuf + W_IN, nullptr, xz_b, ROWS, D_, 2 * DI_, D_);
    // 3. causal conv + SiLU (rolling-window) -> bf16
    conv_silu_kernel<<<dim3(2, B_), dim3(128), 0, stream>>>(xz_b, conv_w, conv_b, uc_b);
    // 4. x_proj (BK=64 swz, split-K x16, atomic f32): xdbl = uc @ x_proj_W^T  (3968 x 96)
    hipMemsetAsync(xdbl, 0, (size_t)ROWS * 96 * sizeof(float), stream);
    gemm128_bk64<0, false, 2><<<dim3(1, 31, 16), dim3(256), 0, stream>>>(
        uc_b, wbuf + W_XP, nullptr, xdbl, ROWS, DI_, DTR_ + 2 * DS_, 128);
    // 5. dt_proj (BK=64 swz, softplus) -> bf16   (3968 x 2048, K=64)
    dtext_kernel<<<dim3(ROWS * 16 / 256), dim3(256), 0, stream>>>(xdbl, dtb);
    gemm128_bk64<2, true, 1><<<dim3(16, 31, 1), dim3(256), 0, stream>>>(
        dtb, wbuf + W_DT, dt_projb, dt_b, ROWS, DTR_, DI_, DTR_);
    // 6. selective scan (+ skip + gate) -> bf16 y
    scan_kernel<<<dim3(B_ * DI_ / 256), dim3(256), 0, stream>>>(
        dt_b, uc_b, xz_b, xdbl, A_log, D_ssm, y_b);
    // 7. out_proj (BK=64 swz, split-K z=2) -> bf16 partials p0,p1   (3968 x 1024, K=2048)
    gemm128_bk64<0, false, 4><<<dim3(8, 31, 2), dim3(256), 0, stream>>>(
        y_b, wbuf + W_OUT, nullptr, pq, ROWS, DI_, D_, 1024);
    // 8. fused combine + LN2: x2 = x + p0 + p1, h2 = LN(x2) -> bf16
    ln2_fuse_kernel<<<dim3(ROWS), dim3(256), 0, stream>>>(
        x, pq, pq + (size_t)ROWS * D_, n2w, n2b, x2, h_b);
    // 9. ffn1 (BK=64 swz) + bias + SiLU -> bf16   (3968 x 2048, K=1024), 496 blocks
    gemm128_bk64<1, true, 1><<<dim3(16, 31, 1), dim3(256), 0, stream>>>(
        h_b, wbuf + W_F1, ffn_b1, uc_b, ROWS, D_, 2 * D_, D_);
    // 10. ffn2 (BK=64 swz, split-K z=2) -> bf16 partials q0,q1   (3968 x 1024, K=2048)
    gemm128_bk64<0, false, 4><<<dim3(8, 31, 2), dim3(256), 0, stream>>>(
        uc_b, wbuf + W_F2, nullptr, pq, ROWS, 2 * D_, D_, 1024);
    // 11. combine: x3 = x2 + q0 + q1 + b2 -> d_out
    add3_bias_kernel<<<dim3(ROWS * D_ / 4 / 256), dim3(256), 0, stream>>>(
        x2, pq, pq + (size_t)ROWS * D_, ffn_b2, x3);
    // 12. classifier layer 1: split-K MFMA, reg-prefetch pipeline + swizzle
    hipMemsetAsync(clsh, 0, (size_t)B_ * D_ * sizeof(float), stream);
    gemm_cls_mfma<<<dim3(1024 / 128, KCLS / KCH), dim3(256), 0, stream>>>(x3, cls_W1, clsh);
    // 13. classifier layer 2
    cls2_kernel<<<dim3(B_), dim3(256), 0, stream>>>(clsh, cls_b1, cls_W2, cls_b2, outv);
}